// Round 1
// baseline (187.792 us; speedup 1.0000x reference)
//
#include <hip/hip_runtime.h>

#define HOLE_P 0.05f
#define TILE 64
#define HALO 8
#define LW 80          // LDS tile width/height (TILE + 2*HALO)
#define LN 6400        // LW*LW
#define NWORDS 1600    // LN/4

// Kernel 1: u_small[i][j] = OR over 16 channels of (hole_u[c][2i][2j] < p)
__global__ void k_usmall(const float* __restrict__ hole_u, unsigned char* __restrict__ u_small) {
    int g = blockIdx.x * blockDim.x + threadIdx.x;       // 0 .. 512*512-1
    int i = g >> 9, j = g & 511;
    const float* base = hole_u + i * 2048 + j * 2;
    unsigned char inv = 0;
#pragma unroll
    for (int c = 0; c < 16; ++c)
        inv |= (base[c * 1048576] < HOLE_P) ? 1 : 0;
    u_small[g] = inv;
}

// Kernel 2: d_small = cross-dilate(u_small), zero pad
__global__ void k_dsmall(const unsigned char* __restrict__ u_small, unsigned char* __restrict__ d_small) {
    int g = blockIdx.x * blockDim.x + threadIdx.x;
    int i = g >> 9, j = g & 511;
    unsigned char d = u_small[g];
    if (i > 0)   d |= u_small[g - 512];
    if (i < 511) d |= u_small[g + 512];
    if (j > 0)   d |= u_small[g - 1];
    if (j < 511) d |= u_small[g + 1];
    d_small[g] = d;
}

// Kernel 3: per-channel 64x64 tiles with halo 8; full 8-iter propagation in LDS.
__global__ __launch_bounds__(256) void k_fill(
    const float* __restrict__ x, const float* __restrict__ hole_u,
    const unsigned char* __restrict__ d_small, float* __restrict__ out)
{
    __shared__ float v[LN];
    __shared__ unsigned char wb[2][LN];   // w: 0=fillable, 1=source/filled, 2=out-of-image sentinel
    __shared__ unsigned char invm[LN];
    __shared__ int changed;

    const int tid = threadIdx.x;
    const int c   = blockIdx.z;
    const int by0 = blockIdx.y * TILE;
    const int bx0 = blockIdx.x * TILE;
    const float* xc = x + c * 1048576;
    const float* uc = hole_u + c * 1048576;
    float* oc = out + c * 1048576;

    // ---- init: load, compute source set, early-write x to out for interior ----
    for (int p = tid; p < LN; p += 256) {
        int ly = p / LW, lx = p - ly * LW;
        int gy = by0 - HALO + ly, gx = bx0 - HALO + lx;
        float vv = 0.0f; unsigned char ww = 2, ib = 0;
        if (gy >= 0 && gy < 1024 && gx >= 0 && gx < 1024) {
            int gi = gy * 1024 + gx;
            float uu = uc[gi];
            float xx = xc[gi];
            ib = (uu < HOLE_P) ? 1 : 0;
            unsigned char dd = d_small[(gy >> 1) * 512 + (gx >> 1)];
            bool corner = (gy == 0 || gy == 1023) && (gx == 0 || gx == 1023);
            bool srcp = (dd && !ib) || corner;
            ww = srcp ? 1 : 0;
            vv = (srcp && !ib) ? xx : 0.0f;
            if (ly >= HALO && ly < HALO + TILE && lx >= HALO && lx < HALO + TILE)
                oc[gi] = xx;   // valid pixels keep x; invalid overwritten below
        }
        v[p] = vv; wb[0][p] = ww; invm[p] = ib;
    }

    // ---- 8 Jacobi iterations, early exit when stationary (then identity) ----
    int cur = 0;
    for (int it = 0; it < 8; ++it) {
        if (tid == 0) changed = 0;
        __syncthreads();                      // (A) init/prev writes + reset visible
        int any = 0;
        const unsigned char* wc = wb[cur];
        unsigned char* wn = wb[cur ^ 1];
        for (int wp = tid; wp < NWORDS; wp += 256) {
            unsigned int cw = ((const unsigned int*)wc)[wp];
            // fast path: no zero byte -> nothing fillable in these 4 pixels
            if (((cw - 0x01010101u) & ~cw & 0x80808080u) == 0u) {
                ((unsigned int*)wn)[wp] = cw;
                continue;
            }
            int pb = wp * 4;
            int ly = pb / LW;                 // LW%4==0: word never crosses rows
            unsigned int outw = 0;
#pragma unroll
            for (int b = 0; b < 4; ++b) {
                int p = pb + b;
                unsigned char wv = (cw >> (8 * b)) & 0xffu;
                unsigned char nb = wv;
                if (wv == 0) {
                    int lx = p - ly * LW;
                    float s = 0.0f; int cnt = 0;
                    if (ly > 0      && wc[p - LW] == 1) { s += v[p - LW]; ++cnt; }
                    if (ly < LW - 1 && wc[p + LW] == 1) { s += v[p + LW]; ++cnt; }
                    if (lx > 0      && wc[p - 1]  == 1) { s += v[p - 1];  ++cnt; }
                    if (lx < LW - 1 && wc[p + 1]  == 1) { s += v[p + 1];  ++cnt; }
                    if (cnt > 0) {
                        v[p] = s / (float)cnt;   // reads gated by OLD w: race-free in-place
                        nb = 1; any = 1;
                    }
                }
                outw |= ((unsigned int)nb) << (8 * b);
            }
            ((unsigned int*)wn)[wp] = outw;
        }
        if (any) changed = 1;                 // benign LDS race (all write 1)
        __syncthreads();                      // (B) sets + v/w writes visible
        int stop = (changed == 0);
        __syncthreads();                      // (C) everyone read flag before next reset
        if (stop) break;
        cur ^= 1;
    }

    // ---- final scatter: invalid interior pixels get propagated v ----
    for (int p = tid; p < LN; p += 256) {
        if (!invm[p]) continue;
        int ly = p / LW, lx = p - ly * LW;
        if (ly < HALO || ly >= HALO + TILE || lx < HALO || lx >= HALO + TILE) continue;
        int gy = by0 - HALO + ly, gx = bx0 - HALO + lx;
        oc[gy * 1024 + gx] = v[p];
    }
}

extern "C" void kernel_launch(void* const* d_in, const int* in_sizes, int n_in,
                              void* d_out, int out_size, void* d_ws, size_t ws_size,
                              hipStream_t stream) {
    (void)in_sizes; (void)n_in; (void)out_size; (void)ws_size;
    const float* x      = (const float*)d_in[0];
    const float* hole_u = (const float*)d_in[1];
    float* out = (float*)d_out;
    unsigned char* u_small = (unsigned char*)d_ws;            // 512*512 = 256 KiB
    unsigned char* d_small = u_small + 262144;                // 512*512 = 256 KiB

    k_usmall<<<1024, 256, 0, stream>>>(hole_u, u_small);
    k_dsmall<<<1024, 256, 0, stream>>>(u_small, d_small);
    dim3 grid(16, 16, 16);   // tiles_x, tiles_y, channels
    k_fill<<<grid, 256, 0, stream>>>(x, hole_u, d_small, out);
}

// Round 2
// 119.333 us; speedup vs baseline: 1.5737x; 1.5737x over previous
//
#include <hip/hip_runtime.h>

#define HOLE_P 0.05f
#define TILE 64
#define HALO 8
#define LW 80          // TILE + 2*HALO
#define LN 6400        // LW*LW
#define NWORDS 1600    // LN/4
#define NG 1600        // 4-pixel groups per tile (80 rows * 20 groups)

// Kernel 1: u_small[i][j] = OR over 16 channels of (hole_u[c][2i][2j] < p)
// vectorized: each thread produces 2 adjacent outputs via one float4 per channel
__global__ void k_usmall(const float* __restrict__ hole_u, unsigned char* __restrict__ u_small) {
    int g = blockIdx.x * blockDim.x + threadIdx.x;   // 0 .. 512*256-1
    int i = g >> 8;            // row 0..511
    int k = g & 255;           // pair index; output cols 2k, 2k+1
    const float* base = hole_u + i * 2048 + k * 4;   // cols 4k..4k+3 of row 2i
    unsigned char inv0 = 0, inv1 = 0;
#pragma unroll
    for (int c = 0; c < 16; ++c) {
        float4 f = *reinterpret_cast<const float4*>(base + c * 1048576);
        inv0 |= (f.x < HOLE_P) ? 1 : 0;   // col 4k   = 2*(2k)
        inv1 |= (f.z < HOLE_P) ? 1 : 0;   // col 4k+2 = 2*(2k+1)
    }
    *reinterpret_cast<uchar2*>(u_small + i * 512 + k * 2) = make_uchar2(inv0, inv1);
}

// Kernel 2: d_small = cross-dilate(u_small), zero pad (tiny: 256KB in/out)
__global__ void k_dsmall(const unsigned char* __restrict__ u_small, unsigned char* __restrict__ d_small) {
    int g = blockIdx.x * blockDim.x + threadIdx.x;
    int i = g >> 9, j = g & 511;
    unsigned char d = u_small[g];
    if (i > 0)   d |= u_small[g - 512];
    if (i < 511) d |= u_small[g + 512];
    if (j > 0)   d |= u_small[g - 1];
    if (j < 511) d |= u_small[g + 1];
    d_small[g] = d;
}

// Kernel 3: per-channel 64x64 tiles, halo 8, full 8-iter propagation in LDS.
// w byte encoding: bit7 = invalid(pixel was NaN); low 7 bits = state:
//   0 = unfilled, 1 = init source, it+2 = filled at iteration it, 0x7f = out-of-image
// Contributor test at iteration it: (state-1) <= it  (unsigned).
// In-place single-buffer update is race-free & deterministic: concurrent readers
// of a byte being written see either 0 or it+2 — both fail the contributor test.
__global__ __launch_bounds__(256, 5) void k_fill(
    const float* __restrict__ x, const float* __restrict__ hole_u,
    const unsigned char* __restrict__ d_small, float* __restrict__ out)
{
    __shared__ float v[LN];
    __shared__ unsigned char w[LN];
    __shared__ int changed[8];

    const int tid = threadIdx.x;
    const int c   = blockIdx.z;
    const int by0 = blockIdx.y * TILE;
    const int bx0 = blockIdx.x * TILE;
    const float* xc = x + c * 1048576;
    const float* uc = hole_u + c * 1048576;
    float* oc = out + c * 1048576;

    if (tid < 8) changed[tid] = 0;

    // ---- init: 4-pixel groups, float4 loads, early-write x to out interior ----
    for (int g = tid; g < NG; g += 256) {
        int ly  = g / 20;
        int lx0 = (g - ly * 20) * 4;
        int gy  = by0 - HALO + ly;
        int gx0 = bx0 - HALO + lx0;           // multiple of 4 -> group whole-in/out in x
        int p0  = ly * LW + lx0;
        float4 vv = make_float4(0.f, 0.f, 0.f, 0.f);
        unsigned int wword = 0x7f7f7f7fu;     // out-of-image sentinel
        if (gy >= 0 && gy < 1024 && gx0 >= 0 && gx0 < 1024) {
            int gi = gy * 1024 + gx0;
            float4 xx = *reinterpret_cast<const float4*>(xc + gi);
            float4 uu = *reinterpret_cast<const float4*>(uc + gi);
            unsigned short ds2 = *reinterpret_cast<const unsigned short*>(
                d_small + (gy >> 1) * 512 + (gx0 >> 1));
            float xv[4] = {xx.x, xx.y, xx.z, xx.w};
            float uv[4] = {uu.x, uu.y, uu.z, uu.w};
            unsigned char dd[4] = {(unsigned char)(ds2 & 0xff), (unsigned char)(ds2 & 0xff),
                                   (unsigned char)(ds2 >> 8),   (unsigned char)(ds2 >> 8)};
            bool rowEdge = (gy == 0) || (gy == 1023);
            float vf[4];
            wword = 0;
#pragma unroll
            for (int b = 0; b < 4; ++b) {
                bool ib = uv[b] < HOLE_P;
                bool corner = rowEdge && ((gx0 + b) == 0 || (gx0 + b) == 1023);
                bool srcp = (dd[b] != 0 && !ib) || corner;
                unsigned int wb_ = srcp ? 1u : 0u;
                if (ib) wb_ |= 0x80u;
                wword |= wb_ << (8 * b);
                vf[b] = (srcp && !ib) ? xv[b] : 0.0f;
            }
            vv = make_float4(vf[0], vf[1], vf[2], vf[3]);
            if (ly >= HALO && ly < HALO + TILE && lx0 >= HALO && lx0 < HALO + TILE)
                *reinterpret_cast<float4*>(oc + gi) = xx;  // valid pixels keep x
        }
        *reinterpret_cast<float4*>(&v[p0]) = vv;
        *reinterpret_cast<unsigned int*>(&w[p0]) = wword;
    }
    __syncthreads();

    // ---- 8 Jacobi iterations, in-place, 1 barrier each, early exit ----
    for (int it = 0; it < 8; ++it) {
        int any = 0;
        unsigned int thr = (unsigned int)it;
        for (int wp = tid; wp < NWORDS; wp += 256) {
            unsigned int cw = *reinterpret_cast<const unsigned int*>(&w[wp * 4]);
            unsigned int st = cw & 0x7f7f7f7fu;
            // fast path: no state-0 byte -> nothing fillable here, no writes
            if ((((st - 0x01010101u) & ~st) & 0x80808080u) == 0u) continue;
            int p0 = wp * 4;
            int ly = p0 / LW;                  // LW%4==0: word never crosses rows
            int lx0 = p0 - ly * LW;
#pragma unroll
            for (int b = 0; b < 4; ++b) {
                if (((st >> (8 * b)) & 0x7fu) != 0u) continue;
                int p = p0 + b;
                int lx = lx0 + b;
                float s = 0.0f; int cnt = 0;
                if (ly > 0)      { unsigned int s2 = w[p - LW] & 0x7fu; if (s2 - 1u <= thr) { s += v[p - LW]; ++cnt; } }
                if (ly < LW - 1) { unsigned int s2 = w[p + LW] & 0x7fu; if (s2 - 1u <= thr) { s += v[p + LW]; ++cnt; } }
                if (lx > 0)      { unsigned int s2 = w[p - 1]  & 0x7fu; if (s2 - 1u <= thr) { s += v[p - 1];  ++cnt; } }
                if (lx < LW - 1) { unsigned int s2 = w[p + 1]  & 0x7fu; if (s2 - 1u <= thr) { s += v[p + 1];  ++cnt; } }
                if (cnt > 0) {
                    v[p] = s / (float)cnt;     // reads gated by old state: race-free
                    w[p] = (unsigned char)(((cw >> (8 * b)) & 0x80u) | (unsigned int)(it + 2));
                    any = 1;
                }
            }
        }
        if (any) changed[it] = 1;              // benign all-write-1 race
        __syncthreads();                       // writes visible + changed final
        if (changed[it] == 0) break;           // stationary -> identity afterwards
    }

    // ---- final scatter: invalid interior pixels get propagated v ----
    // (loop exit above always passed through a barrier; v/w reads are safe)
    for (int g = tid; g < 1024; g += 256) {    // 64 rows * 16 groups interior
        int ly  = HALO + (g >> 4);
        int lx0 = HALO + ((g & 15) << 2);
        int p0  = ly * LW + lx0;
        unsigned int cw = *reinterpret_cast<const unsigned int*>(&w[p0]);
        unsigned int invb = cw & 0x80808080u;
        if (invb == 0u) continue;
        int gy = by0 - HALO + ly, gx0 = bx0 - HALO + lx0;
        int gi = gy * 1024 + gx0;
#pragma unroll
        for (int b = 0; b < 4; ++b)
            if (invb & (0x80u << (8 * b))) oc[gi + b] = v[p0 + b];
    }
}

extern "C" void kernel_launch(void* const* d_in, const int* in_sizes, int n_in,
                              void* d_out, int out_size, void* d_ws, size_t ws_size,
                              hipStream_t stream) {
    (void)in_sizes; (void)n_in; (void)out_size; (void)ws_size;
    const float* x      = (const float*)d_in[0];
    const float* hole_u = (const float*)d_in[1];
    float* out = (float*)d_out;
    unsigned char* u_small = (unsigned char*)d_ws;            // 256 KiB
    unsigned char* d_small = u_small + 262144;                // 256 KiB

    k_usmall<<<512, 256, 0, stream>>>(hole_u, u_small);       // 512*256 threads
    k_dsmall<<<1024, 256, 0, stream>>>(u_small, d_small);
    dim3 grid(16, 16, 16);   // tiles_x, tiles_y, channels
    k_fill<<<grid, 256, 0, stream>>>(x, hole_u, d_small, out);
}

// Round 4
// 86.383 us; speedup vs baseline: 2.1740x; 1.3814x over previous
//
#include <hip/hip_runtime.h>

#define HOLE_P 0.05f
#define TILE 64
#define HALO 8
#define LW 80          // TILE + 2*HALO
#define LN 6400        // LW*LW
#define NWORDS 1600    // LN/4
#define NG 1600        // 4-pixel groups per LDS tile

// Kernel 1: pack invalid = (hole_u < p) into bitmask, 8 px per byte, flat [c][y][x/8]
__global__ void k_mask(const float* __restrict__ hole_u, unsigned char* __restrict__ inv_mask) {
    int t = blockIdx.x * blockDim.x + threadIdx.x;    // 0 .. 2M-1
    const float* base = hole_u + (size_t)t * 8;
    float4 a = *reinterpret_cast<const float4*>(base);
    float4 b = *reinterpret_cast<const float4*>(base + 4);
    unsigned int m = (a.x < HOLE_P ? 1u : 0u)  | (a.y < HOLE_P ? 2u : 0u)  |
                     (a.z < HOLE_P ? 4u : 0u)  | (a.w < HOLE_P ? 8u : 0u)  |
                     (b.x < HOLE_P ? 16u : 0u) | (b.y < HOLE_P ? 32u : 0u) |
                     (b.z < HOLE_P ? 64u : 0u) | (b.w < HOLE_P ? 128u : 0u);
    inv_mask[t] = (unsigned char)m;
}

// Kernel 2: u_small[i][j] = OR over channels of invalid[c][2i][2j] (even bits of mask bytes)
__global__ void k_us(const unsigned char* __restrict__ inv_mask, unsigned char* __restrict__ u_small) {
    int t = blockIdx.x * blockDim.x + threadIdx.x;    // 0 .. 65535
    int i  = t >> 7;                                  // small row 0..511
    int jb = t & 127;                                 // mask byte col (full cols 8jb..8jb+7)
    const unsigned char* p = inv_mask + (i << 8) + jb;  // full row 2i (row stride 128 B)
    unsigned int b = 0;
#pragma unroll
    for (int c = 0; c < 16; ++c) b |= p[c * 131072];
    unsigned int o = (b & 1u) | (((b >> 2) & 1u) << 8) | (((b >> 4) & 1u) << 16) | (((b >> 6) & 1u) << 24);
    *reinterpret_cast<unsigned int*>(u_small + i * 512 + jb * 4) = o;
}

// Kernel 3: d_small = cross-dilate(u_small), zero pad
__global__ void k_dil(const unsigned char* __restrict__ u_small, unsigned char* __restrict__ d_small) {
    int g = blockIdx.x * blockDim.x + threadIdx.x;
    int i = g >> 9, j = g & 511;
    unsigned char d = u_small[g];
    if (i > 0)   d |= u_small[g - 512];
    if (i < 511) d |= u_small[g + 512];
    if (j > 0)   d |= u_small[g - 1];
    if (j < 511) d |= u_small[g + 1];
    d_small[g] = d;
}

// Kernel 4: per-channel 64x64 tiles, halo 8; full propagation in LDS.
// w byte: bit7 = invalid(was NaN); low7 state: 0 = fillable (invalid OR valid
// relay with d=0), 1 = source, it+2 = filled at iter it, 0x7f = out-of-image.
// Valid d=0 pixels are relays (w0=0, v0=0) exactly as in the reference; their
// output stays x (early-write), only bit7 pixels get scattered v.
// Contributor test at iteration it: (state-1) <= it (unsigned).
// In-place single-buffer update is race-free & deterministic: concurrent
// readers of a byte being filled see 0 or it+2 — both fail the test.
__global__ __launch_bounds__(512, 8) void k_fill(
    const float* __restrict__ x, const unsigned char* __restrict__ inv_mask,
    const unsigned char* __restrict__ d_small, float* __restrict__ out)
{
    __shared__ float v[LN];
    __shared__ unsigned char w[LN];
    __shared__ int changed[8];

    const int tid = threadIdx.x;
    const int c   = blockIdx.z;
    const int by0 = blockIdx.y * TILE;
    const int bx0 = blockIdx.x * TILE;
    const float* xc = x + c * 1048576;
    const unsigned char* mc = inv_mask + c * 131072;
    float* oc = out + c * 1048576;

    if (tid < 8) changed[tid] = 0;

    // ---- init: 4-px groups; float4 x load, mask nibble, early-write interior x ----
    for (int g = tid; g < NG; g += 512) {
        int ly  = g / 20;
        int lx0 = (g - ly * 20) * 4;
        int gy  = by0 - HALO + ly;
        int gx0 = bx0 - HALO + lx0;          // multiple of 4: group whole-in/out in x
        int p0  = ly * LW + lx0;
        float4 vv = make_float4(0.f, 0.f, 0.f, 0.f);
        unsigned int ww = 0x7f7f7f7fu;       // out-of-image sentinel
        if ((unsigned)gy < 1024u && (unsigned)gx0 < 1024u) {
            int gi = gy * 1024 + gx0;
            float4 xx = *reinterpret_cast<const float4*>(xc + gi);
            unsigned int nib = (mc[(gy << 7) + (gx0 >> 3)] >> (gx0 & 7)) & 0xfu;
            unsigned short ds2 = *reinterpret_cast<const unsigned short*>(
                d_small + ((gy >> 1) << 9) + (gx0 >> 1));
            bool rowEdge = (gy == 0) | (gy == 1023);
            float xv[4] = {xx.x, xx.y, xx.z, xx.w};
            float vf[4];
            ww = 0;
#pragma unroll
            for (int b = 0; b < 4; ++b) {
                bool ib = (nib >> b) & 1u;
                bool dd = (((b < 2) ? (ds2 & 0xffu) : (ds2 >> 8)) != 0u);
                bool corner = rowEdge & ((gx0 + b == 0) | (gx0 + b == 1023));
                bool srcp = (dd & !ib) | corner;
                unsigned int wb = (srcp ? 1u : 0u) | (ib ? 0x80u : 0u);
                ww |= wb << (8 * b);
                vf[b] = (srcp & !ib) ? xv[b] : 0.0f;   // invalid corner: source, v=0
            }
            vv = make_float4(vf[0], vf[1], vf[2], vf[3]);
            if (ly >= HALO && ly < HALO + TILE && lx0 >= HALO && lx0 < HALO + TILE)
                *reinterpret_cast<float4*>(oc + gi) = xx;  // valid pixels keep x
        }
        *reinterpret_cast<float4*>(&v[p0]) = vv;
        *reinterpret_cast<unsigned int*>(&w[p0]) = ww;
    }
    __syncthreads();

    // ---- Jacobi iterations, in-place, 1 barrier each, per-block early exit ----
    for (int it = 0; it < 8; ++it) {
        int any = 0;
        unsigned int thr = (unsigned int)it;
        for (int wp = tid; wp < NWORDS; wp += 512) {
            unsigned int cw = *reinterpret_cast<const unsigned int*>(&w[wp * 4]);
            unsigned int st = cw & 0x7f7f7f7fu;
            // fast path: no state-0 byte -> nothing fillable here, no writes
            if ((((st - 0x01010101u) & ~st) & 0x80808080u) == 0u) continue;
            int p0 = wp * 4;
            int ly = p0 / LW;                 // LW%4==0: word never crosses rows
            int lx0 = p0 - ly * LW;
#pragma unroll
            for (int b = 0; b < 4; ++b) {
                if (((st >> (8 * b)) & 0x7fu) != 0u) continue;
                int p = p0 + b, lx = lx0 + b;
                float s = 0.0f; int cnt = 0;
                if (ly > 0)      { unsigned int q = w[p - LW] & 0x7fu; if (q - 1u <= thr) { s += v[p - LW]; ++cnt; } }
                if (ly < LW - 1) { unsigned int q = w[p + LW] & 0x7fu; if (q - 1u <= thr) { s += v[p + LW]; ++cnt; } }
                if (lx > 0)      { unsigned int q = w[p - 1]  & 0x7fu; if (q - 1u <= thr) { s += v[p - 1];  ++cnt; } }
                if (lx < LW - 1) { unsigned int q = w[p + 1]  & 0x7fu; if (q - 1u <= thr) { s += v[p + 1];  ++cnt; } }
                if (cnt > 0) {
                    v[p] = s / (float)cnt;    // reads gated by old state: race-free
                    w[p] = (unsigned char)(((cw >> (8 * b)) & 0x80u) | (unsigned int)(it + 2));
                    any = 1;
                }
            }
        }
        if (any) changed[it] = 1;             // benign all-write-1 race
        __syncthreads();
        if (changed[it] == 0) break;          // stationary -> identity afterwards
    }

    // ---- final scatter: invalid interior pixels get propagated v ----
    for (int g = tid; g < 1024; g += 512) {   // 64 rows * 16 groups interior
        int ly  = HALO + (g >> 4);
        int lx0 = HALO + ((g & 15) << 2);
        int p0  = ly * LW + lx0;
        unsigned int cw = *reinterpret_cast<const unsigned int*>(&w[p0]);
        unsigned int invb = cw & 0x80808080u;
        if (invb == 0u) continue;
        int gy = by0 - HALO + ly, gx0 = bx0 - HALO + lx0;
        int gi = gy * 1024 + gx0;
#pragma unroll
        for (int b = 0; b < 4; ++b)
            if (invb & (0x80u << (8 * b))) oc[gi + b] = v[p0 + b];
    }
}

extern "C" void kernel_launch(void* const* d_in, const int* in_sizes, int n_in,
                              void* d_out, int out_size, void* d_ws, size_t ws_size,
                              hipStream_t stream) {
    (void)in_sizes; (void)n_in; (void)out_size; (void)ws_size;
    const float* x      = (const float*)d_in[0];
    const float* hole_u = (const float*)d_in[1];
    float* out = (float*)d_out;
    unsigned char* u_small  = (unsigned char*)d_ws;           // 256 KiB
    unsigned char* d_small  = u_small + 262144;               // 256 KiB
    unsigned char* inv_mask = d_small + 262144;               // 2 MiB

    k_mask<<<8192, 256, 0, stream>>>(hole_u, inv_mask);       // 2M threads, 8 px each
    k_us  <<<256, 256, 0, stream>>>(inv_mask, u_small);
    k_dil <<<1024, 256, 0, stream>>>(u_small, d_small);
    dim3 grid(16, 16, 16);   // tiles_x, tiles_y, channels
    k_fill<<<grid, 512, 0, stream>>>(x, inv_mask, d_small, out);
}

// Round 5
// 77.862 us; speedup vs baseline: 2.4119x; 1.1094x over previous
//
#include <hip/hip_runtime.h>

#define HOLE_P 0.05f
#define TILE 64
#define HALO 8
#define LW 80          // TILE + 2*HALO
#define LN 6400        // LW*LW
#define NWORDS 1600    // LN/4

// Kernel 1: pack invalid = (hole_u < p) into bitmask, 8 px per byte, flat [c][y][x/8]
__global__ void k_mask(const float* __restrict__ hole_u, unsigned char* __restrict__ inv_mask) {
    int t = blockIdx.x * blockDim.x + threadIdx.x;    // 0 .. 2M-1
    const float* base = hole_u + (size_t)t * 8;
    float4 a = *reinterpret_cast<const float4*>(base);
    float4 b = *reinterpret_cast<const float4*>(base + 4);
    unsigned int m = (a.x < HOLE_P ? 1u : 0u)  | (a.y < HOLE_P ? 2u : 0u)  |
                     (a.z < HOLE_P ? 4u : 0u)  | (a.w < HOLE_P ? 8u : 0u)  |
                     (b.x < HOLE_P ? 16u : 0u) | (b.y < HOLE_P ? 32u : 0u) |
                     (b.z < HOLE_P ? 64u : 0u) | (b.w < HOLE_P ? 128u : 0u);
    inv_mask[t] = (unsigned char)m;
}

// Kernel 2: u_small[i][j] = OR over channels of invalid[c][2i][2j] (even bits of mask bytes)
__global__ void k_us(const unsigned char* __restrict__ inv_mask, unsigned char* __restrict__ u_small) {
    int t = blockIdx.x * blockDim.x + threadIdx.x;    // 0 .. 65535
    int i  = t >> 7;                                  // small row 0..511
    int jb = t & 127;                                 // mask byte col (full cols 8jb..8jb+7)
    const unsigned char* p = inv_mask + (i << 8) + jb;  // full row 2i (row stride 128 B)
    unsigned int b = 0;
#pragma unroll
    for (int c = 0; c < 16; ++c) b |= p[c * 131072];
    unsigned int o = (b & 1u) | (((b >> 2) & 1u) << 8) | (((b >> 4) & 1u) << 16) | (((b >> 6) & 1u) << 24);
    *reinterpret_cast<unsigned int*>(u_small + i * 512 + jb * 4) = o;
}

// Kernel 3: d_small = cross-dilate(u_small), zero pad
__global__ void k_dil(const unsigned char* __restrict__ u_small, unsigned char* __restrict__ d_small) {
    int g = blockIdx.x * blockDim.x + threadIdx.x;
    int i = g >> 9, j = g & 511;
    unsigned char d = u_small[g];
    if (i > 0)   d |= u_small[g - 512];
    if (i < 511) d |= u_small[g + 512];
    if (j > 0)   d |= u_small[g - 1];
    if (j < 511) d |= u_small[g + 1];
    d_small[g] = d;
}

// Kernel 4: per-channel 64x64 tiles, halo 8; full propagation in LDS.
// w byte: bit7 = invalid(was NaN); low7 state: 0 = fillable (invalid OR valid
// relay with d=0), 1 = source, it+2 = filled at iter it, 0x7f = out-of-image.
// Each thread keeps its 2 interior float4 x-groups in registers; epilogue is
// one blended store out = bit7 ? v : x_reg (relays -> x even if filled; sources
// have v==x; invalid -> propagated v). No early-write, no scatter.
// In-place single-buffer update is race-free & deterministic: concurrent
// readers of a byte being filled see 0 or it+2 — both fail the contributor test.
__global__ __launch_bounds__(512, 8) void k_fill(
    const float* __restrict__ x, const unsigned char* __restrict__ inv_mask,
    const unsigned char* __restrict__ d_small, float* __restrict__ out)
{
    __shared__ float v[LN];
    __shared__ unsigned char w[LN];
    __shared__ int changed[8];

    const int tid = threadIdx.x;
    const int c   = blockIdx.z;
    const int by0 = blockIdx.y * TILE;
    const int bx0 = blockIdx.x * TILE;
    const float* xc = x + c * 1048576;
    const unsigned char* mc = inv_mask + c * 131072;
    float* oc = out + c * 1048576;
    const bool cornerTile = ((blockIdx.x == 0) | (blockIdx.x == 15)) &
                            ((blockIdx.y == 0) | (blockIdx.y == 15));

    if (tid < 8) changed[tid] = 0;

    // ---- interior init: 1024 groups, 2/thread, no bounds checks; x kept in regs ----
    float4 xr[2];
#pragma unroll
    for (int k = 0; k < 2; ++k) {
        int g  = tid + k * 512;          // 0..1023
        int r  = g >> 4;                 // interior row 0..63
        int cg = g & 15;                 // interior col group
        int gy = by0 + r;
        int gx0 = bx0 + cg * 4;
        int gi = gy * 1024 + gx0;
        float4 xx = *reinterpret_cast<const float4*>(xc + gi);
        xr[k] = xx;
        unsigned int nib = (mc[(gy << 7) + (gx0 >> 3)] >> (gx0 & 7)) & 0xfu;
        unsigned short ds2 = *reinterpret_cast<const unsigned short*>(
            d_small + ((gy >> 1) << 9) + (gx0 >> 1));
        unsigned int dbits = ((ds2 & 0xffu) ? 0x3u : 0u) | ((ds2 & 0xff00u) ? 0xcu : 0u);
        unsigned int src = dbits & ~nib & 0xfu;
        if (cornerTile) {
            if ((gy == 0) | (gy == 1023))
                src |= (gx0 == 0 ? 1u : 0u) | (gx0 == 1020 ? 8u : 0u);  // corners forced source
        }
        unsigned int ww = ((src * 0x204081u) & 0x01010101u) |
                          (((nib * 0x204081u) & 0x01010101u) << 7);
        unsigned int vs = src & ~nib;    // v = x only for valid sources
        float4 vv;
        vv.x = (vs & 1u) ? xx.x : 0.0f;
        vv.y = (vs & 2u) ? xx.y : 0.0f;
        vv.z = (vs & 4u) ? xx.z : 0.0f;
        vv.w = (vs & 8u) ? xx.w : 0.0f;
        int p0 = (HALO + r) * LW + HALO + cg * 4;
        *reinterpret_cast<float4*>(&v[p0]) = vv;
        *reinterpret_cast<unsigned int*>(&w[p0]) = ww;
    }

    // ---- halo init: 576 groups (rows 0-7,72-79 full; rows 8-71 edge cols) ----
    for (int h = tid; h < 576; h += 512) {
        int ly, lxg;
        if (h < 160)      { ly = h / 20;                lxg = h - (h / 20) * 20; }
        else if (h < 320) { int t2 = h - 160; ly = 72 + t2 / 20; lxg = t2 - (t2 / 20) * 20; }
        else              { int t2 = h - 320; ly = 8 + (t2 >> 2); int q = t2 & 3; lxg = q < 2 ? q : q + 16; }
        int gy  = by0 - HALO + ly;
        int gx0 = bx0 - HALO + lxg * 4;
        int p0  = ly * LW + lxg * 4;
        float4 vv = make_float4(0.f, 0.f, 0.f, 0.f);
        unsigned int ww = 0x7f7f7f7fu;   // out-of-image sentinel
        if ((unsigned)gy < 1024u && (unsigned)gx0 < 1024u) {
            int gi = gy * 1024 + gx0;
            float4 xx = *reinterpret_cast<const float4*>(xc + gi);
            unsigned int nib = (mc[(gy << 7) + (gx0 >> 3)] >> (gx0 & 7)) & 0xfu;
            unsigned short ds2 = *reinterpret_cast<const unsigned short*>(
                d_small + ((gy >> 1) << 9) + (gx0 >> 1));
            unsigned int dbits = ((ds2 & 0xffu) ? 0x3u : 0u) | ((ds2 & 0xff00u) ? 0xcu : 0u);
            unsigned int src = dbits & ~nib & 0xfu;   // corners never in halo (proven)
            ww = ((src * 0x204081u) & 0x01010101u) |
                 (((nib * 0x204081u) & 0x01010101u) << 7);
            vv.x = (src & 1u) ? xx.x : 0.0f;
            vv.y = (src & 2u) ? xx.y : 0.0f;
            vv.z = (src & 4u) ? xx.z : 0.0f;
            vv.w = (src & 8u) ? xx.w : 0.0f;
        }
        *reinterpret_cast<float4*>(&v[p0]) = vv;
        *reinterpret_cast<unsigned int*>(&w[p0]) = ww;
    }
    __syncthreads();

    // ---- Jacobi iterations, in-place, 1 barrier each, per-block early exit ----
    for (int it = 0; it < 8; ++it) {
        int any = 0;
        unsigned int thr = (unsigned int)it;
        for (int wp = tid; wp < NWORDS; wp += 512) {
            unsigned int cw = *reinterpret_cast<const unsigned int*>(&w[wp * 4]);
            unsigned int st = cw & 0x7f7f7f7fu;
            // fast path: no state-0 byte -> nothing fillable here, no writes
            if ((((st - 0x01010101u) & ~st) & 0x80808080u) == 0u) continue;
            int p0 = wp * 4;
            int ly = p0 / LW;                 // LW%4==0: word never crosses rows
            int lx0 = p0 - ly * LW;
#pragma unroll
            for (int b = 0; b < 4; ++b) {
                if (((st >> (8 * b)) & 0x7fu) != 0u) continue;
                int p = p0 + b, lx = lx0 + b;
                float s = 0.0f; int cnt = 0;
                if (ly > 0)      { unsigned int q = w[p - LW] & 0x7fu; if (q - 1u <= thr) { s += v[p - LW]; ++cnt; } }
                if (ly < LW - 1) { unsigned int q = w[p + LW] & 0x7fu; if (q - 1u <= thr) { s += v[p + LW]; ++cnt; } }
                if (lx > 0)      { unsigned int q = w[p - 1]  & 0x7fu; if (q - 1u <= thr) { s += v[p - 1];  ++cnt; } }
                if (lx < LW - 1) { unsigned int q = w[p + 1]  & 0x7fu; if (q - 1u <= thr) { s += v[p + 1];  ++cnt; } }
                if (cnt > 0) {
                    v[p] = s / (float)cnt;    // reads gated by old state: race-free
                    w[p] = (unsigned char)(((cw >> (8 * b)) & 0x80u) | (unsigned int)(it + 2));
                    any = 1;
                }
            }
        }
        if (any) changed[it] = 1;             // benign all-write-1 race
        __syncthreads();
        if (changed[it] == 0) break;          // stationary -> identity afterwards
    }

    // ---- epilogue: one blended coalesced store of the whole interior ----
#pragma unroll
    for (int k = 0; k < 2; ++k) {
        int g  = tid + k * 512;
        int r  = g >> 4;
        int cg = g & 15;
        int p0 = (HALO + r) * LW + HALO + cg * 4;
        unsigned int cw = *reinterpret_cast<const unsigned int*>(&w[p0]);
        float4 vv = *reinterpret_cast<const float4*>(&v[p0]);
        float4 xx = xr[k];
        float4 o;
        o.x = (cw & 0x00000080u) ? vv.x : xx.x;
        o.y = (cw & 0x00008000u) ? vv.y : xx.y;
        o.z = (cw & 0x00800000u) ? vv.z : xx.z;
        o.w = (cw & 0x80000000u) ? vv.w : xx.w;
        *reinterpret_cast<float4*>(oc + (by0 + r) * 1024 + bx0 + cg * 4) = o;
    }
}

extern "C" void kernel_launch(void* const* d_in, const int* in_sizes, int n_in,
                              void* d_out, int out_size, void* d_ws, size_t ws_size,
                              hipStream_t stream) {
    (void)in_sizes; (void)n_in; (void)out_size; (void)ws_size;
    const float* x      = (const float*)d_in[0];
    const float* hole_u = (const float*)d_in[1];
    float* out = (float*)d_out;
    unsigned char* u_small  = (unsigned char*)d_ws;           // 256 KiB
    unsigned char* d_small  = u_small + 262144;               // 256 KiB
    unsigned char* inv_mask = d_small + 262144;               // 2 MiB

    k_mask<<<8192, 256, 0, stream>>>(hole_u, inv_mask);       // 2M threads, 8 px each
    k_us  <<<256, 256, 0, stream>>>(inv_mask, u_small);
    k_dil <<<1024, 256, 0, stream>>>(u_small, d_small);
    dim3 grid(16, 16, 16);   // tiles_x, tiles_y, channels
    k_fill<<<grid, 512, 0, stream>>>(x, inv_mask, d_small, out);
}

// Round 7
// 72.173 us; speedup vs baseline: 2.6020x; 1.0788x over previous
//
#include <hip/hip_runtime.h>

#define HOLE_P 0.05f
#define TILE 64
#define HALO 8
#define LW 80          // TILE + 2*HALO
#define LN 6400        // LW*LW
#define NWORDS 1600    // LN/4

// Kernel 1: pack invalid = (hole_u < p) into bitmask, 8 px per byte, flat [c][y][x/8]
__global__ void k_mask(const float* __restrict__ hole_u, unsigned char* __restrict__ inv_mask) {
    int t = blockIdx.x * blockDim.x + threadIdx.x;    // 0 .. 2M-1
    const float* base = hole_u + (size_t)t * 8;
    float4 a = *reinterpret_cast<const float4*>(base);
    float4 b = *reinterpret_cast<const float4*>(base + 4);
    unsigned int m = (a.x < HOLE_P ? 1u : 0u)  | (a.y < HOLE_P ? 2u : 0u)  |
                     (a.z < HOLE_P ? 4u : 0u)  | (a.w < HOLE_P ? 8u : 0u)  |
                     (b.x < HOLE_P ? 16u : 0u) | (b.y < HOLE_P ? 32u : 0u) |
                     (b.z < HOLE_P ? 64u : 0u) | (b.w < HOLE_P ? 128u : 0u);
    inv_mask[t] = (unsigned char)m;
}

// Kernel 2: u_small[i][j] = OR over channels of invalid[c][2i][2j] (even bits of mask bytes)
__global__ void k_us(const unsigned char* __restrict__ inv_mask, unsigned char* __restrict__ u_small) {
    int t = blockIdx.x * blockDim.x + threadIdx.x;    // 0 .. 65535
    int i  = t >> 7;                                  // small row 0..511
    int jb = t & 127;                                 // mask byte col (full cols 8jb..8jb+7)
    const unsigned char* p = inv_mask + (i << 8) + jb;  // full row 2i (row stride 128 B)
    unsigned int b = 0;
#pragma unroll
    for (int c = 0; c < 16; ++c) b |= p[c * 131072];
    unsigned int o = (b & 1u) | (((b >> 2) & 1u) << 8) | (((b >> 4) & 1u) << 16) | (((b >> 6) & 1u) << 24);
    *reinterpret_cast<unsigned int*>(u_small + i * 512 + jb * 4) = o;
}

// Kernel 3: d_small = cross-dilate(u_small), zero pad
__global__ void k_dil(const unsigned char* __restrict__ u_small, unsigned char* __restrict__ d_small) {
    int g = blockIdx.x * blockDim.x + threadIdx.x;
    int i = g >> 9, j = g & 511;
    unsigned char d = u_small[g];
    if (i > 0)   d |= u_small[g - 512];
    if (i < 511) d |= u_small[g + 512];
    if (j > 0)   d |= u_small[g - 1];
    if (j < 511) d |= u_small[g + 1];
    d_small[g] = d;
}

// Process one 4-byte state word at iteration `it`.
// Return bits: 1 = word still has fillable (state-0) bytes,
//              2 = filled something, 4 = unfilled INVALID byte in an
//              interior-overlapping word (gates loop continuation).
// NOTE: the (st-0x0101..) zero-byte trick is exact only at WORD level (bytes
// are <=0x7f); per-byte flags have borrow-chain false positives (a state-1
// source above a zero byte would flag). Per-byte test must be the exact one.
__device__ __forceinline__ unsigned int proc_word(
    float* v, unsigned char* w, int p0, int ly, int lx0, int it, bool pint)
{
    unsigned int cw = *reinterpret_cast<const unsigned int*>(&w[p0]);
    unsigned int st = cw & 0x7f7f7f7fu;
    if ((((st - 0x01010101u) & ~st) & 0x80808080u) == 0u) return 0u;  // word-level: exact
    unsigned int ret = 0u;
    unsigned int thr = (unsigned int)it;
#pragma unroll
    for (int b = 0; b < 4; ++b) {
        if (((st >> (8 * b)) & 0x7fu) != 0u) continue;   // exact per-byte test
        int p = p0 + b, lx = lx0 + b;
        float s = 0.0f; int cnt = 0;
        if (ly > 0)      { unsigned int q = w[p - LW] & 0x7fu; if (q - 1u <= thr) { s += v[p - LW]; ++cnt; } }
        if (ly < LW - 1) { unsigned int q = w[p + LW] & 0x7fu; if (q - 1u <= thr) { s += v[p + LW]; ++cnt; } }
        if (lx > 0)      { unsigned int q = w[p - 1]  & 0x7fu; if (q - 1u <= thr) { s += v[p - 1];  ++cnt; } }
        if (lx < LW - 1) { unsigned int q = w[p + 1]  & 0x7fu; if (q - 1u <= thr) { s += v[p + 1];  ++cnt; } }
        if (cnt > 0) {
            v[p] = s / (float)cnt;            // reads gated by old state: race-free
            w[p] = (unsigned char)(((cw >> (8 * b)) & 0x80u) | (unsigned int)(it + 2));
            ret |= 2u;
        } else {
            ret |= 1u;                        // still fillable
            if (pint && ((cw >> (8 * b)) & 0x80u)) ret |= 4u;  // relevant pending invalid
        }
    }
    return ret;
}

// Kernel 4: per-channel 64x64 tiles, halo 8; full propagation in LDS.
// w byte: bit7 = invalid(was NaN); low7 state: 0 = fillable, 1 = source,
// it+2 = filled at iter it, 0x7f = out-of-image. Filled values are immutable;
// output reads v only at interior bit7 pixels -> loop can stop as soon as no
// interior invalid byte has state 0 (pending exit), or when nothing fills
// anywhere (stationary exit). Word active-sets shrink monotonically and are
// tracked in per-thread register masks (fixed word->thread partition).
__global__ __launch_bounds__(512, 8) void k_fill(
    const float* __restrict__ x, const unsigned char* __restrict__ inv_mask,
    const unsigned char* __restrict__ d_small, float* __restrict__ out)
{
    __shared__ float v[LN];
    __shared__ unsigned char w[LN];
    __shared__ int chgf[8];
    __shared__ int pendf[8];

    const int tid = threadIdx.x;
    const int c   = blockIdx.z;
    const int by0 = blockIdx.y * TILE;
    const int bx0 = blockIdx.x * TILE;
    const float* xc = x + c * 1048576;
    const unsigned char* mc = inv_mask + c * 131072;
    float* oc = out + c * 1048576;
    const bool cornerTile = ((blockIdx.x == 0) | (blockIdx.x == 15)) &
                            ((blockIdx.y == 0) | (blockIdx.y == 15));

    if (tid < 8) { chgf[tid] = 0; pendf[tid] = 0; }

    // ---- interior init: 1024 groups, 2/thread, no bounds checks; x kept in regs ----
    float4 xr[2];
#pragma unroll
    for (int k = 0; k < 2; ++k) {
        int g  = tid + k * 512;          // 0..1023
        int r  = g >> 4;                 // interior row 0..63
        int cg = g & 15;                 // interior col group
        int gy = by0 + r;
        int gx0 = bx0 + cg * 4;
        int gi = gy * 1024 + gx0;
        float4 xx = *reinterpret_cast<const float4*>(xc + gi);
        xr[k] = xx;
        unsigned int nib = (mc[(gy << 7) + (gx0 >> 3)] >> (gx0 & 7)) & 0xfu;
        unsigned short ds2 = *reinterpret_cast<const unsigned short*>(
            d_small + ((gy >> 1) << 9) + (gx0 >> 1));
        unsigned int dbits = ((ds2 & 0xffu) ? 0x3u : 0u) | ((ds2 & 0xff00u) ? 0xcu : 0u);
        unsigned int src = dbits & ~nib & 0xfu;
        if (cornerTile) {
            if ((gy == 0) | (gy == 1023))
                src |= (gx0 == 0 ? 1u : 0u) | (gx0 == 1020 ? 8u : 0u);  // corners forced source
        }
        unsigned int ww = ((src * 0x204081u) & 0x01010101u) |
                          (((nib * 0x204081u) & 0x01010101u) << 7);
        unsigned int vs = src & ~nib;    // v = x only for valid sources
        float4 vv;
        vv.x = (vs & 1u) ? xx.x : 0.0f;
        vv.y = (vs & 2u) ? xx.y : 0.0f;
        vv.z = (vs & 4u) ? xx.z : 0.0f;
        vv.w = (vs & 8u) ? xx.w : 0.0f;
        int p0 = (HALO + r) * LW + HALO + cg * 4;
        *reinterpret_cast<float4*>(&v[p0]) = vv;
        *reinterpret_cast<unsigned int*>(&w[p0]) = ww;
    }

    // ---- halo init: 576 groups (rows 0-7,72-79 full; rows 8-71 edge cols) ----
    for (int h = tid; h < 576; h += 512) {
        int ly, lxg;
        if (h < 160)      { ly = h / 20;                lxg = h - (h / 20) * 20; }
        else if (h < 320) { int t2 = h - 160; ly = 72 + t2 / 20; lxg = t2 - (t2 / 20) * 20; }
        else              { int t2 = h - 320; ly = 8 + (t2 >> 2); int q = t2 & 3; lxg = q < 2 ? q : q + 16; }
        int gy  = by0 - HALO + ly;
        int gx0 = bx0 - HALO + lxg * 4;
        int p0  = ly * LW + lxg * 4;
        float4 vv = make_float4(0.f, 0.f, 0.f, 0.f);
        unsigned int ww = 0x7f7f7f7fu;   // out-of-image sentinel
        if ((unsigned)gy < 1024u && (unsigned)gx0 < 1024u) {
            int gi = gy * 1024 + gx0;
            float4 xx = *reinterpret_cast<const float4*>(xc + gi);
            unsigned int nib = (mc[(gy << 7) + (gx0 >> 3)] >> (gx0 & 7)) & 0xfu;
            unsigned short ds2 = *reinterpret_cast<const unsigned short*>(
                d_small + ((gy >> 1) << 9) + (gx0 >> 1));
            unsigned int dbits = ((ds2 & 0xffu) ? 0x3u : 0u) | ((ds2 & 0xff00u) ? 0xcu : 0u);
            unsigned int src = dbits & ~nib & 0xfu;   // corners never in halo (proven)
            ww = ((src * 0x204081u) & 0x01010101u) |
                 (((nib * 0x204081u) & 0x01010101u) << 7);
            vv.x = (src & 1u) ? xx.x : 0.0f;
            vv.y = (src & 2u) ? xx.y : 0.0f;
            vv.z = (src & 4u) ? xx.z : 0.0f;
            vv.w = (src & 8u) ? xx.w : 0.0f;
        }
        *reinterpret_cast<float4*>(&v[p0]) = vv;
        *reinterpret_cast<unsigned int*>(&w[p0]) = ww;
    }
    __syncthreads();

    // ---- slot geometry (fixed word->thread partition) ----
    int p0_[4], ly_[4], lx_[4]; bool pi_[4];
#pragma unroll
    for (int k = 0; k < 4; ++k) {
        int wp = tid + k * 512;
        int p0 = wp * 4;
        int ly = p0 / LW;
        int lx0 = p0 - ly * LW;
        p0_[k] = p0; ly_[k] = ly; lx_[k] = lx0;
        pi_[k] = (ly >= HALO) & (ly < HALO + TILE) & (lx0 + 3 >= HALO) & (lx0 < HALO + TILE);
    }
    const bool has4 = (tid < 64);        // word 1536+tid exists only for tid<64

    // ---- iteration 0: full sweep, build register active mask ----
    unsigned int act = 0;
    {
        unsigned int anyf = 0;
#pragma unroll
        for (int k = 0; k < 3; ++k) {
            unsigned int r = proc_word(v, w, p0_[k], ly_[k], lx_[k], 0, pi_[k]);
            anyf |= r;
            if (r & 1u) act |= 1u << k;
        }
        if (has4) {
            unsigned int r = proc_word(v, w, p0_[3], ly_[3], lx_[3], 0, pi_[3]);
            anyf |= r;
            if (r & 1u) act |= 8u;
        }
        if (anyf & 2u) chgf[0] = 1;
        if (anyf & 4u) pendf[0] = 1;
        __syncthreads();
    }
    if (chgf[0] != 0 && pendf[0] != 0) {
        // ---- iterations 1..7: only register-flagged active words ----
        for (int it = 1; it < 8; ++it) {
            unsigned int anyf = 0;
#pragma unroll
            for (int k = 0; k < 4; ++k) {
                if (act & (1u << k)) {
                    unsigned int r = proc_word(v, w, p0_[k], ly_[k], lx_[k], it, pi_[k]);
                    anyf |= r;
                    if (!(r & 1u)) act &= ~(1u << k);
                }
            }
            if (anyf & 2u) chgf[it] = 1;
            if (anyf & 4u) pendf[it] = 1;
            __syncthreads();
            if (chgf[it] == 0 || pendf[it] == 0) break;
        }
    }

    // ---- epilogue: one blended coalesced store of the whole interior ----
#pragma unroll
    for (int k = 0; k < 2; ++k) {
        int g  = tid + k * 512;
        int r  = g >> 4;
        int cg = g & 15;
        int p0 = (HALO + r) * LW + HALO + cg * 4;
        unsigned int cw = *reinterpret_cast<const unsigned int*>(&w[p0]);
        float4 vv = *reinterpret_cast<const float4*>(&v[p0]);
        float4 xx = xr[k];
        float4 o;
        o.x = (cw & 0x00000080u) ? vv.x : xx.x;
        o.y = (cw & 0x00008000u) ? vv.y : xx.y;
        o.z = (cw & 0x00800000u) ? vv.z : xx.z;
        o.w = (cw & 0x80000000u) ? vv.w : xx.w;
        *reinterpret_cast<float4*>(oc + (by0 + r) * 1024 + bx0 + cg * 4) = o;
    }
}

extern "C" void kernel_launch(void* const* d_in, const int* in_sizes, int n_in,
                              void* d_out, int out_size, void* d_ws, size_t ws_size,
                              hipStream_t stream) {
    (void)in_sizes; (void)n_in; (void)out_size; (void)ws_size;
    const float* x      = (const float*)d_in[0];
    const float* hole_u = (const float*)d_in[1];
    float* out = (float*)d_out;
    unsigned char* u_small  = (unsigned char*)d_ws;           // 256 KiB
    unsigned char* d_small  = u_small + 262144;               // 256 KiB
    unsigned char* inv_mask = d_small + 262144;               // 2 MiB

    k_mask<<<8192, 256, 0, stream>>>(hole_u, inv_mask);       // 2M threads, 8 px each
    k_us  <<<256, 256, 0, stream>>>(inv_mask, u_small);
    k_dil <<<1024, 256, 0, stream>>>(u_small, d_small);
    dim3 grid(16, 16, 16);   // tiles_x, tiles_y, channels
    k_fill<<<grid, 512, 0, stream>>>(x, inv_mask, d_small, out);
}

// Round 9
// 71.941 us; speedup vs baseline: 2.6104x; 1.0032x over previous
//
#include <hip/hip_runtime.h>

#define HOLE_P 0.05f
#define TW 64          // tile width
#define TH 32          // tile height
#define HALO 8
#define LW 80          // region width  (TW + 2*HALO)
#define RH 48          // region height (TH + 2*HALO)
#define LN 3840        // LW*RH
#define NWORDS 960     // LN/4

// Kernel 1: pack invalid = (hole_u < p) into bitmask, 8 px per byte, flat [c][y][x/8]
__global__ void k_mask(const float* __restrict__ hole_u, unsigned char* __restrict__ inv_mask) {
    int t = blockIdx.x * blockDim.x + threadIdx.x;    // 0 .. 2M-1
    const float* base = hole_u + (size_t)t * 8;
    float4 a = *reinterpret_cast<const float4*>(base);
    float4 b = *reinterpret_cast<const float4*>(base + 4);
    unsigned int m = (a.x < HOLE_P ? 1u : 0u)  | (a.y < HOLE_P ? 2u : 0u)  |
                     (a.z < HOLE_P ? 4u : 0u)  | (a.w < HOLE_P ? 8u : 0u)  |
                     (b.x < HOLE_P ? 16u : 0u) | (b.y < HOLE_P ? 32u : 0u) |
                     (b.z < HOLE_P ? 64u : 0u) | (b.w < HOLE_P ? 128u : 0u);
    inv_mask[t] = (unsigned char)m;
}

// Kernel 2: u_small[i][j] = OR over channels of invalid[c][2i][2j] (even bits of mask bytes)
__global__ void k_us(const unsigned char* __restrict__ inv_mask, unsigned char* __restrict__ u_small) {
    int t = blockIdx.x * blockDim.x + threadIdx.x;    // 0 .. 65535
    int i  = t >> 7;                                  // small row 0..511
    int jb = t & 127;                                 // mask byte col (full cols 8jb..8jb+7)
    const unsigned char* p = inv_mask + (i << 8) + jb;  // full row 2i (row stride 128 B)
    unsigned int b = 0;
#pragma unroll
    for (int c = 0; c < 16; ++c) b |= p[c * 131072];
    unsigned int o = (b & 1u) | (((b >> 2) & 1u) << 8) | (((b >> 4) & 1u) << 16) | (((b >> 6) & 1u) << 24);
    *reinterpret_cast<unsigned int*>(u_small + i * 512 + jb * 4) = o;
}

// Kernel 3: d_small = cross-dilate(u_small), zero pad
__global__ void k_dil(const unsigned char* __restrict__ u_small, unsigned char* __restrict__ d_small) {
    int g = blockIdx.x * blockDim.x + threadIdx.x;
    int i = g >> 9, j = g & 511;
    unsigned char d = u_small[g];
    if (i > 0)   d |= u_small[g - 512];
    if (i < 511) d |= u_small[g + 512];
    if (j > 0)   d |= u_small[g - 1];
    if (j < 511) d |= u_small[g + 1];
    d_small[g] = d;
}

// Halo group index h (0..447) -> (row, col-group) in the 80x48 region:
// h<160: rows 0-7 full; h<320: rows 40-47 full; else rows 8-39 edge cols.
__device__ __forceinline__ void halo_map(int h, int& ly, int& lxg) {
    if (h < 160)      { ly = h / 20;                lxg = h - (h / 20) * 20; }
    else if (h < 320) { int t2 = h - 160; ly = 40 + t2 / 20; lxg = t2 - (t2 / 20) * 20; }
    else              { int t2 = h - 320; ly = 8 + (t2 >> 2); int q = t2 & 3; lxg = q < 2 ? q : q + 16; }
}

// State-word encode from src/invalid nibbles (bit i -> byte i).
__device__ __forceinline__ unsigned int enc_w(unsigned int src, unsigned int nib) {
    return ((src * 0x204081u) & 0x01010101u) | (((nib * 0x204081u) & 0x01010101u) << 7);
}

// Process one 4-byte state word at iteration `it`.
// Return bits: 1 = word still has fillable (state-0) bytes,
//              2 = filled something, 4 = unfilled INVALID byte in an
//              interior-overlapping word (gates loop continuation).
// The (st-0x0101..) zero-byte trick is exact only at WORD level (bytes <=0x7f);
// per-byte it has borrow false positives -> per-byte test must be exact.
__device__ __forceinline__ unsigned int proc_word(
    float* v, unsigned char* w, int p0, int ly, int lx0, int it, bool pint)
{
    unsigned int cw = *reinterpret_cast<const unsigned int*>(&w[p0]);
    unsigned int st = cw & 0x7f7f7f7fu;
    if ((((st - 0x01010101u) & ~st) & 0x80808080u) == 0u) return 0u;  // word-level: exact
    unsigned int ret = 0u;
    unsigned int thr = (unsigned int)it;
#pragma unroll
    for (int b = 0; b < 4; ++b) {
        if (((st >> (8 * b)) & 0x7fu) != 0u) continue;   // exact per-byte test
        int p = p0 + b, lx = lx0 + b;
        float s = 0.0f; int cnt = 0;
        if (ly > 0)      { unsigned int q = w[p - LW] & 0x7fu; if (q - 1u <= thr) { s += v[p - LW]; ++cnt; } }
        if (ly < RH - 1) { unsigned int q = w[p + LW] & 0x7fu; if (q - 1u <= thr) { s += v[p + LW]; ++cnt; } }
        if (lx > 0)      { unsigned int q = w[p - 1]  & 0x7fu; if (q - 1u <= thr) { s += v[p - 1];  ++cnt; } }
        if (lx < LW - 1) { unsigned int q = w[p + 1]  & 0x7fu; if (q - 1u <= thr) { s += v[p + 1];  ++cnt; } }
        if (cnt > 0) {
            v[p] = s / (float)cnt;            // reads gated by old state: race-free
            w[p] = (unsigned char)(((cw >> (8 * b)) & 0x80u) | (unsigned int)(it + 2));
            ret |= 2u;
        } else {
            ret |= 1u;                        // still fillable
            if (pint && ((cw >> (8 * b)) & 0x80u)) ret |= 4u;  // relevant pending invalid
        }
    }
    return ret;
}

// Kernel 4: per-channel 64x32 tiles, halo 8; full propagation in LDS.
// 256-thread blocks, 18.9 KB LDS -> 8 blocks/CU (8 independent barrier domains
// per CU keep HBM busy across other blocks' barrier/LDS phases).
// w byte: bit7 = invalid; low7: 0 = fillable, 1 = source, it+2 = filled at it,
// 0x7f = out-of-image. Pending-interior + stationary early exits (states are
// monotone; filled values immutable). Fixed word->thread partition with
// register active masks. Epilogue: blended store out = bit7 ? v : x_reg.
__global__ __launch_bounds__(256, 8) void k_fill(
    const float* __restrict__ x, const unsigned char* __restrict__ inv_mask,
    const unsigned char* __restrict__ d_small, float* __restrict__ out)
{
    __shared__ float v[LN];
    __shared__ unsigned char w[LN];
    __shared__ int chgf[8];
    __shared__ int pendf[8];

    const int tid = threadIdx.x;
    const int c   = blockIdx.z;
    const int by0 = blockIdx.y * TH;
    const int bx0 = blockIdx.x * TW;
    const float* xc = x + c * 1048576;
    const unsigned char* mc = inv_mask + c * 131072;
    float* oc = out + c * 1048576;
    const bool cornerTile = ((blockIdx.x == 0) | (blockIdx.x == 15)) &
                            ((blockIdx.y == 0) | (blockIdx.y == 31));

    if (tid < 8) { chgf[tid] = 0; pendf[tid] = 0; }

    // ---- issue ALL global loads first (max memory-level parallelism) ----
    // interior: 2 groups/thread (512 groups of 4 px)
    int r0  = tid >> 4, cg0 = tid & 15;            // k=0: rows 0..15
    int gy0 = by0 + r0,      gx0 = bx0 + cg0 * 4;
    int gy1 = by0 + r0 + 16, gx1 = gx0;            // k=1: rows 16..31
    int gi0 = gy0 * 1024 + gx0;
    int gi1 = gy1 * 1024 + gx1;
    float4 xx0 = *reinterpret_cast<const float4*>(xc + gi0);
    float4 xx1 = *reinterpret_cast<const float4*>(xc + gi1);
    unsigned int mb0 = mc[(gy0 << 7) + (gx0 >> 3)];
    unsigned int mb1 = mc[(gy1 << 7) + (gx1 >> 3)];
    unsigned short dsA = *reinterpret_cast<const unsigned short*>(d_small + ((gy0 >> 1) << 9) + (gx0 >> 1));
    unsigned short dsB = *reinterpret_cast<const unsigned short*>(d_small + ((gy1 >> 1) << 9) + (gx1 >> 1));

    // halo: 448 groups, 2 per thread (hA = tid always, hB = tid+256 for tid<192)
    int aly, alxg, bly, blxg;
    halo_map(tid, aly, alxg);
    const bool hasB = (tid < 192);
    halo_map(hasB ? tid + 256 : 0, bly, blxg);
    int agy  = by0 - HALO + aly,  agx0 = bx0 - HALO + alxg * 4;
    int bgy  = by0 - HALO + bly,  bgx0 = bx0 - HALO + blxg * 4;
    bool ain = ((unsigned)agy < 1024u) & ((unsigned)agx0 < 1024u);
    bool bin = hasB & ((unsigned)bgy < 1024u) & ((unsigned)bgx0 < 1024u);
    float4 axx = make_float4(0.f, 0.f, 0.f, 0.f), bxx = axx;
    unsigned int amb = 0, bmb = 0; unsigned short ads = 0, bds = 0;
    if (ain) {
        int gi = agy * 1024 + agx0;
        axx = *reinterpret_cast<const float4*>(xc + gi);
        amb = mc[(agy << 7) + (agx0 >> 3)];
        ads = *reinterpret_cast<const unsigned short*>(d_small + ((agy >> 1) << 9) + (agx0 >> 1));
    }
    if (bin) {
        int gi = bgy * 1024 + bgx0;
        bxx = *reinterpret_cast<const float4*>(xc + gi);
        bmb = mc[(bgy << 7) + (bgx0 >> 3)];
        bds = *reinterpret_cast<const unsigned short*>(d_small + ((bgy >> 1) << 9) + (bgx0 >> 1));
    }

    // ---- encode + LDS writes ----
    float4 xr[2] = {xx0, xx1};
    {
        unsigned int nib = (mb0 >> (gx0 & 7)) & 0xfu;
        unsigned int dbits = ((dsA & 0xffu) ? 0x3u : 0u) | ((dsA & 0xff00u) ? 0xcu : 0u);
        unsigned int src = dbits & ~nib & 0xfu;
        if (cornerTile && ((gy0 == 0) | (gy0 == 1023)))
            src |= (gx0 == 0 ? 1u : 0u) | (gx0 == 1020 ? 8u : 0u);
        unsigned int vs = src & ~nib;
        float4 vv;
        vv.x = (vs & 1u) ? xx0.x : 0.0f;
        vv.y = (vs & 2u) ? xx0.y : 0.0f;
        vv.z = (vs & 4u) ? xx0.z : 0.0f;
        vv.w = (vs & 8u) ? xx0.w : 0.0f;
        int p0 = (HALO + r0) * LW + HALO + cg0 * 4;
        *reinterpret_cast<float4*>(&v[p0]) = vv;
        *reinterpret_cast<unsigned int*>(&w[p0]) = enc_w(src, nib);
    }
    {
        unsigned int nib = (mb1 >> (gx1 & 7)) & 0xfu;
        unsigned int dbits = ((dsB & 0xffu) ? 0x3u : 0u) | ((dsB & 0xff00u) ? 0xcu : 0u);
        unsigned int src = dbits & ~nib & 0xfu;
        if (cornerTile && ((gy1 == 0) | (gy1 == 1023)))
            src |= (gx1 == 0 ? 1u : 0u) | (gx1 == 1020 ? 8u : 0u);
        unsigned int vs = src & ~nib;
        float4 vv;
        vv.x = (vs & 1u) ? xx1.x : 0.0f;
        vv.y = (vs & 2u) ? xx1.y : 0.0f;
        vv.z = (vs & 4u) ? xx1.z : 0.0f;
        vv.w = (vs & 8u) ? xx1.w : 0.0f;
        int p0 = (HALO + r0 + 16) * LW + HALO + cg0 * 4;
        *reinterpret_cast<float4*>(&v[p0]) = vv;
        *reinterpret_cast<unsigned int*>(&w[p0]) = enc_w(src, nib);
    }
    {   // halo group A (all threads)
        int p0 = aly * LW + alxg * 4;
        float4 vv = make_float4(0.f, 0.f, 0.f, 0.f);
        unsigned int ww = 0x7f7f7f7fu;       // out-of-image sentinel
        if (ain) {
            unsigned int nib = (amb >> (agx0 & 7)) & 0xfu;
            unsigned int dbits = ((ads & 0xffu) ? 0x3u : 0u) | ((ads & 0xff00u) ? 0xcu : 0u);
            unsigned int src = dbits & ~nib & 0xfu;   // corners never in halo (proven)
            ww = enc_w(src, nib);
            vv.x = (src & 1u) ? axx.x : 0.0f;
            vv.y = (src & 2u) ? axx.y : 0.0f;
            vv.z = (src & 4u) ? axx.z : 0.0f;
            vv.w = (src & 8u) ? axx.w : 0.0f;
        }
        *reinterpret_cast<float4*>(&v[p0]) = vv;
        *reinterpret_cast<unsigned int*>(&w[p0]) = ww;
    }
    if (hasB) {   // halo group B (tid < 192)
        int p0 = bly * LW + blxg * 4;
        float4 vv = make_float4(0.f, 0.f, 0.f, 0.f);
        unsigned int ww = 0x7f7f7f7fu;
        if (bin) {
            unsigned int nib = (bmb >> (bgx0 & 7)) & 0xfu;
            unsigned int dbits = ((bds & 0xffu) ? 0x3u : 0u) | ((bds & 0xff00u) ? 0xcu : 0u);
            unsigned int src = dbits & ~nib & 0xfu;
            ww = enc_w(src, nib);
            vv.x = (src & 1u) ? bxx.x : 0.0f;
            vv.y = (src & 2u) ? bxx.y : 0.0f;
            vv.z = (src & 4u) ? bxx.z : 0.0f;
            vv.w = (src & 8u) ? bxx.w : 0.0f;
        }
        *reinterpret_cast<float4*>(&v[p0]) = vv;
        *reinterpret_cast<unsigned int*>(&w[p0]) = ww;
    }
    __syncthreads();

    // ---- slot geometry (fixed word->thread partition: wp = tid + k*256) ----
    int p0_[4], ly_[4], lx_[4]; bool pi_[4];
#pragma unroll
    for (int k = 0; k < 4; ++k) {
        int wp = tid + k * 256;
        int ly = wp / 20;                     // p0/LW, p0 = wp*4, LW = 80
        int lx0 = (wp - ly * 20) * 4;
        p0_[k] = wp * 4; ly_[k] = ly; lx_[k] = lx0;
        pi_[k] = (ly >= HALO) & (ly < HALO + TH) & (lx0 + 3 >= HALO) & (lx0 < HALO + TW);
    }
    const bool has4 = (tid < 192);            // word 768+tid exists only for tid<192

    // ---- iteration 0: full sweep, build register active mask ----
    unsigned int act = 0;
    {
        unsigned int anyf = 0;
#pragma unroll
        for (int k = 0; k < 3; ++k) {
            unsigned int r = proc_word(v, w, p0_[k], ly_[k], lx_[k], 0, pi_[k]);
            anyf |= r;
            if (r & 1u) act |= 1u << k;
        }
        if (has4) {
            unsigned int r = proc_word(v, w, p0_[3], ly_[3], lx_[3], 0, pi_[3]);
            anyf |= r;
            if (r & 1u) act |= 8u;
        }
        if (anyf & 2u) chgf[0] = 1;
        if (anyf & 4u) pendf[0] = 1;
        __syncthreads();
    }
    if (chgf[0] != 0 && pendf[0] != 0) {
        // ---- iterations 1..7: only register-flagged active words ----
        for (int it = 1; it < 8; ++it) {
            unsigned int anyf = 0;
#pragma unroll
            for (int k = 0; k < 4; ++k) {
                if (act & (1u << k)) {
                    unsigned int r = proc_word(v, w, p0_[k], ly_[k], lx_[k], it, pi_[k]);
                    anyf |= r;
                    if (!(r & 1u)) act &= ~(1u << k);
                }
            }
            if (anyf & 2u) chgf[it] = 1;
            if (anyf & 4u) pendf[it] = 1;
            __syncthreads();
            if (chgf[it] == 0 || pendf[it] == 0) break;
        }
    }

    // ---- epilogue: one blended coalesced store of the whole interior ----
#pragma unroll
    for (int k = 0; k < 2; ++k) {
        int r  = r0 + k * 16;
        int p0 = (HALO + r) * LW + HALO + cg0 * 4;
        unsigned int cw = *reinterpret_cast<const unsigned int*>(&w[p0]);
        float4 vv = *reinterpret_cast<const float4*>(&v[p0]);
        float4 xx = xr[k];
        float4 o;
        o.x = (cw & 0x00000080u) ? vv.x : xx.x;
        o.y = (cw & 0x00008000u) ? vv.y : xx.y;
        o.z = (cw & 0x00800000u) ? vv.z : xx.z;
        o.w = (cw & 0x80000000u) ? vv.w : xx.w;
        *reinterpret_cast<float4*>(oc + (by0 + r) * 1024 + bx0 + cg0 * 4) = o;
    }
}

extern "C" void kernel_launch(void* const* d_in, const int* in_sizes, int n_in,
                              void* d_out, int out_size, void* d_ws, size_t ws_size,
                              hipStream_t stream) {
    (void)in_sizes; (void)n_in; (void)out_size; (void)ws_size;
    const float* x      = (const float*)d_in[0];
    const float* hole_u = (const float*)d_in[1];
    float* out = (float*)d_out;
    unsigned char* u_small  = (unsigned char*)d_ws;           // 256 KiB
    unsigned char* d_small  = u_small + 262144;               // 256 KiB
    unsigned char* inv_mask = d_small + 262144;               // 2 MiB

    k_mask<<<8192, 256, 0, stream>>>(hole_u, inv_mask);       // 2M threads, 8 px each
    k_us  <<<256, 256, 0, stream>>>(inv_mask, u_small);
    k_dil <<<1024, 256, 0, stream>>>(u_small, d_small);
    dim3 grid(16, 32, 16);   // tiles_x, tiles_y, channels
    k_fill<<<grid, 256, 0, stream>>>(x, inv_mask, d_small, out);
}

// Round 10
// 54.910 us; speedup vs baseline: 3.4200x; 1.3102x over previous
//
#include <hip/hip_runtime.h>

#define HOLE_P 0.05f
#define TW 64          // tile width
#define TH 32          // tile height
#define HALO 8
#define PRW 88         // padded row: 3 pad + guard + 80 content + guard + 3 pad
#define PRH 50         // guard + 48 content rows + guard
#define PLN 4400       // PRW*PRH
#define PWORDS 1100
#define QCAP 2048      // worklist capacity (typical load ~290, ~35 sigma margin)

// Kernel 1: pack invalid = (hole_u < p) into bitmask, 8 px per byte, flat [c][y][x/8]
__global__ void k_mask(const float* __restrict__ hole_u, unsigned char* __restrict__ inv_mask) {
    int t = blockIdx.x * blockDim.x + threadIdx.x;    // 0 .. 2M-1
    const float* base = hole_u + (size_t)t * 8;
    float4 a = *reinterpret_cast<const float4*>(base);
    float4 b = *reinterpret_cast<const float4*>(base + 4);
    unsigned int m = (a.x < HOLE_P ? 1u : 0u)  | (a.y < HOLE_P ? 2u : 0u)  |
                     (a.z < HOLE_P ? 4u : 0u)  | (a.w < HOLE_P ? 8u : 0u)  |
                     (b.x < HOLE_P ? 16u : 0u) | (b.y < HOLE_P ? 32u : 0u) |
                     (b.z < HOLE_P ? 64u : 0u) | (b.w < HOLE_P ? 128u : 0u);
    inv_mask[t] = (unsigned char)m;
}

// Kernel 2: u_small[i][j] = OR over channels of invalid[c][2i][2j]
__global__ void k_us(const unsigned char* __restrict__ inv_mask, unsigned char* __restrict__ u_small) {
    int t = blockIdx.x * blockDim.x + threadIdx.x;    // 0 .. 65535
    int i  = t >> 7;
    int jb = t & 127;
    const unsigned char* p = inv_mask + (i << 8) + jb;
    unsigned int b = 0;
#pragma unroll
    for (int c = 0; c < 16; ++c) b |= p[c * 131072];
    unsigned int o = (b & 1u) | (((b >> 2) & 1u) << 8) | (((b >> 4) & 1u) << 16) | (((b >> 6) & 1u) << 24);
    *reinterpret_cast<unsigned int*>(u_small + i * 512 + jb * 4) = o;
}

// Kernel 3: d_small = cross-dilate(u_small), zero pad
__global__ void k_dil(const unsigned char* __restrict__ u_small, unsigned char* __restrict__ d_small) {
    int g = blockIdx.x * blockDim.x + threadIdx.x;
    int i = g >> 9, j = g & 511;
    unsigned char d = u_small[g];
    if (i > 0)   d |= u_small[g - 512];
    if (i < 511) d |= u_small[g + 512];
    if (j > 0)   d |= u_small[g - 1];
    if (j < 511) d |= u_small[g + 1];
    d_small[g] = d;
}

// Halo group index h (0..447) -> (row 0..47, col-group 0..19) of the 80x48 content.
__device__ __forceinline__ void halo_map(int h, int& ly, int& lxg) {
    if (h < 160)      { ly = h / 20;                lxg = h - (h / 20) * 20; }
    else if (h < 320) { int t2 = h - 160; ly = 40 + t2 / 20; lxg = t2 - (t2 / 20) * 20; }
    else              { int t2 = h - 320; ly = 8 + (t2 >> 2); int q = t2 & 3; lxg = q < 2 ? q : q + 16; }
}

// State-word encode from src/invalid nibbles (bit i -> byte i).
__device__ __forceinline__ unsigned int enc_w(unsigned int src, unsigned int nib) {
    return ((src * 0x204081u) & 0x01010101u) | (((nib * 0x204081u) & 0x01010101u) << 7);
}

// Kernel 4: per-channel 64x32 tiles, halo 8, guard-ring padded LDS region.
// w byte: bit7 = invalid; low7: 0 = fillable, 1 = source, it+2 = filled at it,
// 0x7f = guard/out-of-image. Fillable pixels (~290/tile) are known at init
// (fill = ~src) -> wave-compacted worklist; iterations process 1 px/lane
// (packed, uniform) instead of divergent full sweeps. States monotone; filled
// entries skipped by 1-byte check. Entry: bits0-12 = p, bit14 = invalid,
// bit15 = pend-relevant (interior & invalid). Exits: nothing filled, or no
// pending interior-invalid left (then interior output is fixed).
__global__ __launch_bounds__(256, 6) void k_fill(
    const float* __restrict__ x, const unsigned char* __restrict__ inv_mask,
    const unsigned char* __restrict__ d_small, float* __restrict__ out)
{
    __shared__ __align__(16) float v[PLN];
    __shared__ unsigned int w32[PWORDS];
    __shared__ unsigned short q[QCAP];
    __shared__ int qn;
    __shared__ int chgf[8], pendf[8];
    unsigned char* w = (unsigned char*)w32;

    const int tid = threadIdx.x;
    const int c   = blockIdx.z;
    const int by0 = blockIdx.y * TH;
    const int bx0 = blockIdx.x * TW;
    const float* xc = x + c * 1048576;
    const unsigned char* mc = inv_mask + c * 131072;
    float* oc = out + c * 1048576;
    const bool cornerTile = ((blockIdx.x == 0) | (blockIdx.x == 15)) &
                            ((blockIdx.y == 0) | (blockIdx.y == 31));

    if (tid < 8) { chgf[tid] = 0; pendf[tid] = 0; }
    if (tid == 0) qn = 0;
    if (tid < 140) {                       // guard ring + pads = 0x7f (sentinel)
        int wi;
        if (tid < 22)      wi = tid;                    // top row words
        else if (tid < 44) wi = 49 * 22 + (tid - 22);   // bottom row words
        else if (tid < 92) wi = (tid - 43) * 22;        // left pads+guard, rows 1..48
        else               wi = (tid - 91) * 22 + 21;   // right guard+pads
        w32[wi] = 0x7f7f7f7fu;
    }
    __syncthreads();                       // qn=0 visible before atomics

    // ---- global loads (max MLP: all issued up front) ----
    int r0  = tid >> 4, cg0 = tid & 15;
    int gy0 = by0 + r0,      gx0 = bx0 + cg0 * 4;
    int gy1 = by0 + r0 + 16;
    float4 xx0 = *reinterpret_cast<const float4*>(xc + gy0 * 1024 + gx0);
    float4 xx1 = *reinterpret_cast<const float4*>(xc + gy1 * 1024 + gx0);
    unsigned int mb0 = mc[(gy0 << 7) + (gx0 >> 3)];
    unsigned int mb1 = mc[(gy1 << 7) + (gx0 >> 3)];
    unsigned short dsA = *reinterpret_cast<const unsigned short*>(d_small + ((gy0 >> 1) << 9) + (gx0 >> 1));
    unsigned short dsB = *reinterpret_cast<const unsigned short*>(d_small + ((gy1 >> 1) << 9) + (gx0 >> 1));

    int aly, alxg, bly, blxg;
    halo_map(tid, aly, alxg);
    const bool hasB = (tid < 192);
    halo_map(hasB ? tid + 256 : 0, bly, blxg);
    int agy  = by0 - HALO + aly,  agx0 = bx0 - HALO + alxg * 4;
    int bgy  = by0 - HALO + bly,  bgx0 = bx0 - HALO + blxg * 4;
    bool ain = ((unsigned)agy < 1024u) & ((unsigned)agx0 < 1024u);
    bool bin = hasB & ((unsigned)bgy < 1024u) & ((unsigned)bgx0 < 1024u);
    float4 axx = make_float4(0.f, 0.f, 0.f, 0.f), bxx = axx;
    unsigned int amb = 0, bmb = 0; unsigned short ads = 0, bds = 0;
    if (ain) {
        int gi = agy * 1024 + agx0;
        axx = *reinterpret_cast<const float4*>(xc + gi);
        amb = mc[(agy << 7) + (agx0 >> 3)];
        ads = *reinterpret_cast<const unsigned short*>(d_small + ((agy >> 1) << 9) + (agx0 >> 1));
    }
    if (bin) {
        int gi = bgy * 1024 + bgx0;
        bxx = *reinterpret_cast<const float4*>(xc + gi);
        bmb = mc[(bgy << 7) + (bgx0 >> 3)];
        bds = *reinterpret_cast<const unsigned short*>(d_small + ((bgy >> 1) << 9) + (bgx0 >> 1));
    }

    // ---- encode + LDS writes; collect fillable nibbles for the worklist ----
    float4 xr[2] = {xx0, xx1};
    unsigned int fN0, fN1, fNA = 0, fNB = 0;   // fillable nibbles
    unsigned int iN0, iN1, iNA = 0, iNB = 0;   // invalid nibbles
    int P0i0, P0i1, P0A, P0B;
    {
        unsigned int nib = (mb0 >> (gx0 & 7)) & 0xfu;
        unsigned int db = ((dsA & 0xffu) ? 0x3u : 0u) | ((dsA & 0xff00u) ? 0xcu : 0u);
        unsigned int src = db & ~nib & 0xfu;
        if (cornerTile && ((gy0 == 0) | (gy0 == 1023)))
            src |= (gx0 == 0 ? 1u : 0u) | (gx0 == 1020 ? 8u : 0u);
        unsigned int vs = src & ~nib;
        float4 vv;
        vv.x = (vs & 1u) ? xx0.x : 0.0f;
        vv.y = (vs & 2u) ? xx0.y : 0.0f;
        vv.z = (vs & 4u) ? xx0.z : 0.0f;
        vv.w = (vs & 8u) ? xx0.w : 0.0f;
        P0i0 = (9 + r0) * PRW + 12 + cg0 * 4;
        *reinterpret_cast<float4*>(&v[P0i0]) = vv;
        w32[P0i0 >> 2] = enc_w(src, nib);
        fN0 = ~src & 0xfu; iN0 = nib;
    }
    {
        unsigned int nib = (mb1 >> (gx0 & 7)) & 0xfu;
        unsigned int db = ((dsB & 0xffu) ? 0x3u : 0u) | ((dsB & 0xff00u) ? 0xcu : 0u);
        unsigned int src = db & ~nib & 0xfu;
        if (cornerTile && ((gy1 == 0) | (gy1 == 1023)))
            src |= (gx0 == 0 ? 1u : 0u) | (gx0 == 1020 ? 8u : 0u);
        unsigned int vs = src & ~nib;
        float4 vv;
        vv.x = (vs & 1u) ? xx1.x : 0.0f;
        vv.y = (vs & 2u) ? xx1.y : 0.0f;
        vv.z = (vs & 4u) ? xx1.z : 0.0f;
        vv.w = (vs & 8u) ? xx1.w : 0.0f;
        P0i1 = (9 + r0 + 16) * PRW + 12 + cg0 * 4;
        *reinterpret_cast<float4*>(&v[P0i1]) = vv;
        w32[P0i1 >> 2] = enc_w(src, nib);
        fN1 = ~src & 0xfu; iN1 = nib;
    }
    {   // halo A (all threads)
        P0A = (aly + 1) * PRW + 4 + alxg * 4;
        float4 vv = make_float4(0.f, 0.f, 0.f, 0.f);
        unsigned int ww = 0x7f7f7f7fu;
        if (ain) {
            unsigned int nib = (amb >> (agx0 & 7)) & 0xfu;
            unsigned int db = ((ads & 0xffu) ? 0x3u : 0u) | ((ads & 0xff00u) ? 0xcu : 0u);
            unsigned int src = db & ~nib & 0xfu;     // corners never in halo
            ww = enc_w(src, nib);
            vv.x = (src & 1u) ? axx.x : 0.0f;
            vv.y = (src & 2u) ? axx.y : 0.0f;
            vv.z = (src & 4u) ? axx.z : 0.0f;
            vv.w = (src & 8u) ? axx.w : 0.0f;
            fNA = ~src & 0xfu; iNA = nib;
        }
        *reinterpret_cast<float4*>(&v[P0A]) = vv;
        w32[P0A >> 2] = ww;
    }
    P0B = (bly + 1) * PRW + 4 + blxg * 4;
    if (hasB) {   // halo B (tid < 192)
        float4 vv = make_float4(0.f, 0.f, 0.f, 0.f);
        unsigned int ww = 0x7f7f7f7fu;
        if (bin) {
            unsigned int nib = (bmb >> (bgx0 & 7)) & 0xfu;
            unsigned int db = ((bds & 0xffu) ? 0x3u : 0u) | ((bds & 0xff00u) ? 0xcu : 0u);
            unsigned int src = db & ~nib & 0xfu;
            ww = enc_w(src, nib);
            vv.x = (src & 1u) ? bxx.x : 0.0f;
            vv.y = (src & 2u) ? bxx.y : 0.0f;
            vv.z = (src & 4u) ? bxx.z : 0.0f;
            vv.w = (src & 8u) ? bxx.w : 0.0f;
            fNB = ~src & 0xfu; iNB = nib;
        }
        *reinterpret_cast<float4*>(&v[P0B]) = vv;
        w32[P0B >> 2] = ww;
    }

    // ---- wave-compacted worklist build (prefix-sum + 1 atomic per wave) ----
    int cnt = __popc(fN0) + __popc(fN1) + __popc(fNA) + __popc(fNB);
    int lane = tid & 63;
    int xsum = cnt;
#pragma unroll
    for (int d = 1; d < 64; d <<= 1) {
        int y = __shfl_up(xsum, d, 64);
        if (lane >= d) xsum += y;
    }
    int base = 0;
    if (lane == 63) base = atomicAdd(&qn, xsum);
    base = __shfl(base, 63, 64);
    int idx = base + (xsum - cnt);
#define PUSH(m_, iv_, pd_, gp_) { unsigned int m = (m_); while (m) {            \
        int b = __builtin_ctz(m); m &= m - 1;                                   \
        unsigned int e = (unsigned int)((gp_) + b) | ((((iv_) >> b) & 1u) << 14)\
                         | ((((pd_) >> b) & 1u) << 15);                         \
        if (idx < QCAP) q[idx] = (unsigned short)e; ++idx; } }
    PUSH(fN0, iN0, fN0 & iN0, P0i0)        // interior: pend = fillable & invalid
    PUSH(fN1, iN1, fN1 & iN1, P0i1)
    PUSH(fNA, iNA, 0u, P0A)                // halo: never pend-relevant
    PUSH(fNB, iNB, 0u, P0B)
#undef PUSH
    __syncthreads();

    const int n = qn;
    if (n <= QCAP) {
        // ---- worklist Jacobi: 1 px/lane, packed; skip filled via state byte ----
        for (int it = 0; it < 8; ++it) {
            int chg = 0, pend = 0;
            unsigned int thr = (unsigned int)it;
            for (int i = tid; i < n; i += 256) {
                unsigned int e = q[i];
                int p = e & 0x1fffu;
                if (w[p] & 0x7fu) continue;            // already filled
                unsigned int qu = w[p - PRW] & 0x7fu;
                unsigned int qd = w[p + PRW] & 0x7fu;
                unsigned int ql = w[p - 1]   & 0x7fu;
                unsigned int qr = w[p + 1]   & 0x7fu;
                bool su = (qu - 1u) <= thr, sd = (qd - 1u) <= thr;
                bool sl = (ql - 1u) <= thr, sr = (qr - 1u) <= thr;
                float s = (su ? v[p - PRW] : 0.0f) + (sd ? v[p + PRW] : 0.0f)
                        + (sl ? v[p - 1]   : 0.0f) + (sr ? v[p + 1]   : 0.0f);
                int cn = (int)su + (int)sd + (int)sl + (int)sr;
                if (cn > 0) {
                    v[p] = s / (float)cn;              // reads gated by old states
                    w[p] = (unsigned char)((((e >> 14) & 1u) << 7) | (unsigned int)(it + 2));
                    chg = 1;
                } else {
                    pend |= (int)((e >> 15) & 1u);
                }
            }
            if (chg)  chgf[it] = 1;                    // benign all-write-1 races
            if (pend) pendf[it] = 1;
            __syncthreads();
            if (chgf[it] == 0 || pendf[it] == 0) break;
        }
    } else {
        // ---- overflow fallback (~never): dense sweeps over all words ----
        for (int it = 0; it < 8; ++it) {
            int chg = 0;
            unsigned int thr = (unsigned int)it;
            for (int wp = tid; wp < PWORDS; wp += 256) {
                unsigned int cw = w32[wp];
                unsigned int st = cw & 0x7f7f7f7fu;
                if ((((st - 0x01010101u) & ~st) & 0x80808080u) == 0u) continue;
                int p0 = wp * 4;
#pragma unroll
                for (int b = 0; b < 4; ++b) {
                    if (((st >> (8 * b)) & 0x7fu) != 0u) continue;  // exact per-byte
                    int p = p0 + b;
                    unsigned int qu = w[p - PRW] & 0x7fu, qd = w[p + PRW] & 0x7fu;
                    unsigned int ql = w[p - 1] & 0x7fu,   qr = w[p + 1] & 0x7fu;
                    bool su = (qu - 1u) <= thr, sd = (qd - 1u) <= thr;
                    bool sl = (ql - 1u) <= thr, sr = (qr - 1u) <= thr;
                    float s = (su ? v[p - PRW] : 0.0f) + (sd ? v[p + PRW] : 0.0f)
                            + (sl ? v[p - 1]   : 0.0f) + (sr ? v[p + 1]   : 0.0f);
                    int cn = (int)su + (int)sd + (int)sl + (int)sr;
                    if (cn > 0) {
                        v[p] = s / (float)cn;
                        w[p] = (unsigned char)(((cw >> (8 * b)) & 0x80u) | (unsigned int)(it + 2));
                        chg = 1;
                    }
                }
            }
            if (chg) chgf[it] = 1;
            __syncthreads();
            if (chgf[it] == 0) break;
        }
    }

    // ---- epilogue: blended coalesced store, out = invalid ? v : x_reg ----
#pragma unroll
    for (int k = 0; k < 2; ++k) {
        int r  = r0 + k * 16;
        int p0 = (9 + r) * PRW + 12 + cg0 * 4;
        unsigned int cw = w32[p0 >> 2];
        float4 vv = *reinterpret_cast<const float4*>(&v[p0]);
        float4 xx = xr[k];
        float4 o;
        o.x = (cw & 0x00000080u) ? vv.x : xx.x;
        o.y = (cw & 0x00008000u) ? vv.y : xx.y;
        o.z = (cw & 0x00800000u) ? vv.z : xx.z;
        o.w = (cw & 0x80000000u) ? vv.w : xx.w;
        *reinterpret_cast<float4*>(oc + (by0 + r) * 1024 + bx0 + cg0 * 4) = o;
    }
}

extern "C" void kernel_launch(void* const* d_in, const int* in_sizes, int n_in,
                              void* d_out, int out_size, void* d_ws, size_t ws_size,
                              hipStream_t stream) {
    (void)in_sizes; (void)n_in; (void)out_size; (void)ws_size;
    const float* x      = (const float*)d_in[0];
    const float* hole_u = (const float*)d_in[1];
    float* out = (float*)d_out;
    unsigned char* u_small  = (unsigned char*)d_ws;           // 256 KiB
    unsigned char* d_small  = u_small + 262144;               // 256 KiB
    unsigned char* inv_mask = d_small + 262144;               // 2 MiB

    k_mask<<<8192, 256, 0, stream>>>(hole_u, inv_mask);       // 2M threads, 8 px each
    k_us  <<<256, 256, 0, stream>>>(inv_mask, u_small);
    k_dil <<<1024, 256, 0, stream>>>(u_small, d_small);
    dim3 grid(16, 32, 16);   // tiles_x, tiles_y, channels
    k_fill<<<grid, 256, 0, stream>>>(x, inv_mask, d_small, out);
}

// Round 11
// 54.363 us; speedup vs baseline: 3.4544x; 1.0101x over previous
//
#include <hip/hip_runtime.h>

#define HOLE_P 0.05f
#define TW 64          // tile width
#define TH 64          // tile height
#define HALO 8
#define PRW 88         // padded row: 3 pad + guard + 80 content + guard + 3 pad
#define PRH 82         // guard + 80 content rows + guard
#define PLN 7216       // PRW*PRH
#define PWORDS 1804
#define QCAP 1536      // worklist capacity (expected ~440, ~27 sigma margin)

// Kernel 1: pack invalid = (hole_u < p) into bitmask, 8 px per byte, flat [c][y][x/8]
__global__ void k_mask(const float* __restrict__ hole_u, unsigned char* __restrict__ inv_mask) {
    int t = blockIdx.x * blockDim.x + threadIdx.x;    // 0 .. 2M-1
    const float* base = hole_u + (size_t)t * 8;
    float4 a = *reinterpret_cast<const float4*>(base);
    float4 b = *reinterpret_cast<const float4*>(base + 4);
    unsigned int m = (a.x < HOLE_P ? 1u : 0u)  | (a.y < HOLE_P ? 2u : 0u)  |
                     (a.z < HOLE_P ? 4u : 0u)  | (a.w < HOLE_P ? 8u : 0u)  |
                     (b.x < HOLE_P ? 16u : 0u) | (b.y < HOLE_P ? 32u : 0u) |
                     (b.z < HOLE_P ? 64u : 0u) | (b.w < HOLE_P ? 128u : 0u);
    inv_mask[t] = (unsigned char)m;
}

// Kernel 2: u_small[i][j] = OR over channels of invalid[c][2i][2j]
__global__ void k_us(const unsigned char* __restrict__ inv_mask, unsigned char* __restrict__ u_small) {
    int t = blockIdx.x * blockDim.x + threadIdx.x;    // 0 .. 65535
    int i  = t >> 7;
    int jb = t & 127;
    const unsigned char* p = inv_mask + (i << 8) + jb;
    unsigned int b = 0;
#pragma unroll
    for (int c = 0; c < 16; ++c) b |= p[c * 131072];
    unsigned int o = (b & 1u) | (((b >> 2) & 1u) << 8) | (((b >> 4) & 1u) << 16) | (((b >> 6) & 1u) << 24);
    *reinterpret_cast<unsigned int*>(u_small + i * 512 + jb * 4) = o;
}

// Kernel 3: d_small = cross-dilate(u_small), zero pad
__global__ void k_dil(const unsigned char* __restrict__ u_small, unsigned char* __restrict__ d_small) {
    int g = blockIdx.x * blockDim.x + threadIdx.x;
    int i = g >> 9, j = g & 511;
    unsigned char d = u_small[g];
    if (i > 0)   d |= u_small[g - 512];
    if (i < 511) d |= u_small[g + 512];
    if (j > 0)   d |= u_small[g - 1];
    if (j < 511) d |= u_small[g + 1];
    d_small[g] = d;
}

// Halo group index h (0..575) -> (row 0..79, col-group 0..19) of 80x80 content.
// h<160: rows 0-7 full; h<320: rows 72-79 full; else rows 8-71, edge groups
// {0,1,18,19} (cols 0-7 and 72-79).
__device__ __forceinline__ void halo_map(int h, int& ly, int& lxg) {
    if (h < 160)      { ly = h / 20;                lxg = h - (h / 20) * 20; }
    else if (h < 320) { int t2 = h - 160; ly = 72 + t2 / 20; lxg = t2 - (t2 / 20) * 20; }
    else              { int t2 = h - 320; ly = 8 + (t2 >> 2); int q = t2 & 3; lxg = q < 2 ? q : q + 16; }
}

// State-word encode from src/invalid nibbles (bit i -> byte i).
__device__ __forceinline__ unsigned int enc_w(unsigned int src, unsigned int nib) {
    return ((src * 0x204081u) & 0x01010101u) | (((nib * 0x204081u) & 0x01010101u) << 7);
}

// Kernel 4: per-channel 64x64 tiles, halo 8, guard-ring padded LDS region.
// w byte: bit7 = invalid; low7: 0 = fillable, 1 = source, it+2 = filled at it,
// 0x7f = guard/out-of-image. Fillable pixels (~440/tile, known at init as
// ~src) go to a wave-compacted worklist; iterations process 1 px/lane.
// States monotone; filled entries skipped by 1-byte check. Entry: bits0-12 = p,
// bit14 = invalid, bit15 = pend-relevant (interior & invalid). Exits: nothing
// filled, or no pending interior-invalid left (interior output then fixed).
__global__ __launch_bounds__(512, 4) void k_fill(
    const float* __restrict__ x, const unsigned char* __restrict__ inv_mask,
    const unsigned char* __restrict__ d_small, float* __restrict__ out)
{
    __shared__ __align__(16) float v[PLN];
    __shared__ unsigned int w32[PWORDS];
    __shared__ unsigned short q[QCAP];
    __shared__ int qn;
    __shared__ int chgf[8], pendf[8];
    unsigned char* w = (unsigned char*)w32;

    const int tid = threadIdx.x;
    const int c   = blockIdx.z;
    const int by0 = blockIdx.y * TH;
    const int bx0 = blockIdx.x * TW;
    const float* xc = x + c * 1048576;
    const unsigned char* mc = inv_mask + c * 131072;
    float* oc = out + c * 1048576;
    const bool cornerTile = ((blockIdx.x == 0) | (blockIdx.x == 15)) &
                            ((blockIdx.y == 0) | (blockIdx.y == 15));

    if (tid < 8) { chgf[tid] = 0; pendf[tid] = 0; }
    if (tid == 0) qn = 0;
    if (tid < 204) {                      // guard ring + pads = 0x7f sentinel
        int wi;
        if (tid < 22)      wi = tid;                         // top row (row 0)
        else if (tid < 44) wi = 81 * 22 + (tid - 22);        // bottom row (row 81)
        else {                                               // rows 1..80, left/right word
            int r = ((tid - 44) >> 1) + 1;
            wi = r * 22 + (((tid - 44) & 1) ? 21 : 0);
        }
        w32[wi] = 0x7f7f7f7fu;
    }
    __syncthreads();                      // qn=0 visible before atomics

    // ---- global loads (max MLP: all issued up front) ----
    // interior: 2 groups/thread (1024 groups of 4 px; k=0 rows 0-31, k=1 rows 32-63)
    int r0  = tid >> 4, cg0 = tid & 15;
    int gy0 = by0 + r0,      gx0 = bx0 + cg0 * 4;
    int gy1 = by0 + r0 + 32;
    float4 xx0 = *reinterpret_cast<const float4*>(xc + gy0 * 1024 + gx0);
    float4 xx1 = *reinterpret_cast<const float4*>(xc + gy1 * 1024 + gx0);
    unsigned int mb0 = mc[(gy0 << 7) + (gx0 >> 3)];
    unsigned int mb1 = mc[(gy1 << 7) + (gx0 >> 3)];
    unsigned short dsA = *reinterpret_cast<const unsigned short*>(d_small + ((gy0 >> 1) << 9) + (gx0 >> 1));
    unsigned short dsB = *reinterpret_cast<const unsigned short*>(d_small + ((gy1 >> 1) << 9) + (gx0 >> 1));

    // halo: 576 groups = hA (all 512 threads) + hB (tid<64 -> h = tid+512)
    int aly, alxg, bly, blxg;
    halo_map(tid, aly, alxg);
    const bool hasB = (tid < 64);
    halo_map(hasB ? tid + 512 : 0, bly, blxg);
    int agy  = by0 - HALO + aly,  agx0 = bx0 - HALO + alxg * 4;
    int bgy  = by0 - HALO + bly,  bgx0 = bx0 - HALO + blxg * 4;
    bool ain = ((unsigned)agy < 1024u) & ((unsigned)agx0 < 1024u);
    bool bin = hasB & ((unsigned)bgy < 1024u) & ((unsigned)bgx0 < 1024u);
    float4 axx = make_float4(0.f, 0.f, 0.f, 0.f), bxx = axx;
    unsigned int amb = 0, bmb = 0; unsigned short ads = 0, bds = 0;
    if (ain) {
        int gi = agy * 1024 + agx0;
        axx = *reinterpret_cast<const float4*>(xc + gi);
        amb = mc[(agy << 7) + (agx0 >> 3)];
        ads = *reinterpret_cast<const unsigned short*>(d_small + ((agy >> 1) << 9) + (agx0 >> 1));
    }
    if (bin) {
        int gi = bgy * 1024 + bgx0;
        bxx = *reinterpret_cast<const float4*>(xc + gi);
        bmb = mc[(bgy << 7) + (bgx0 >> 3)];
        bds = *reinterpret_cast<const unsigned short*>(d_small + ((bgy >> 1) << 9) + (bgx0 >> 1));
    }

    // ---- encode + LDS writes; collect fillable nibbles for the worklist ----
    float4 xr[2] = {xx0, xx1};
    unsigned int fN0, fN1, fNA = 0, fNB = 0;   // fillable nibbles
    unsigned int iN0, iN1, iNA = 0, iNB = 0;   // invalid nibbles
    int P0i0, P0i1, P0A, P0B;
    {
        unsigned int nib = (mb0 >> (gx0 & 7)) & 0xfu;
        unsigned int db = ((dsA & 0xffu) ? 0x3u : 0u) | ((dsA & 0xff00u) ? 0xcu : 0u);
        unsigned int src = db & ~nib & 0xfu;
        if (cornerTile && ((gy0 == 0) | (gy0 == 1023)))
            src |= (gx0 == 0 ? 1u : 0u) | (gx0 == 1020 ? 8u : 0u);
        unsigned int vs = src & ~nib;
        float4 vv;
        vv.x = (vs & 1u) ? xx0.x : 0.0f;
        vv.y = (vs & 2u) ? xx0.y : 0.0f;
        vv.z = (vs & 4u) ? xx0.z : 0.0f;
        vv.w = (vs & 8u) ? xx0.w : 0.0f;
        P0i0 = (9 + r0) * PRW + 12 + cg0 * 4;
        *reinterpret_cast<float4*>(&v[P0i0]) = vv;
        w32[P0i0 >> 2] = enc_w(src, nib);
        fN0 = ~src & 0xfu; iN0 = nib;
    }
    {
        unsigned int nib = (mb1 >> (gx0 & 7)) & 0xfu;
        unsigned int db = ((dsB & 0xffu) ? 0x3u : 0u) | ((dsB & 0xff00u) ? 0xcu : 0u);
        unsigned int src = db & ~nib & 0xfu;
        if (cornerTile && ((gy1 == 0) | (gy1 == 1023)))
            src |= (gx0 == 0 ? 1u : 0u) | (gx0 == 1020 ? 8u : 0u);
        unsigned int vs = src & ~nib;
        float4 vv;
        vv.x = (vs & 1u) ? xx1.x : 0.0f;
        vv.y = (vs & 2u) ? xx1.y : 0.0f;
        vv.z = (vs & 4u) ? xx1.z : 0.0f;
        vv.w = (vs & 8u) ? xx1.w : 0.0f;
        P0i1 = (9 + r0 + 32) * PRW + 12 + cg0 * 4;
        *reinterpret_cast<float4*>(&v[P0i1]) = vv;
        w32[P0i1 >> 2] = enc_w(src, nib);
        fN1 = ~src & 0xfu; iN1 = nib;
    }
    {   // halo A (all threads)
        P0A = (aly + 1) * PRW + 4 + alxg * 4;
        float4 vv = make_float4(0.f, 0.f, 0.f, 0.f);
        unsigned int ww = 0x7f7f7f7fu;
        if (ain) {
            unsigned int nib = (amb >> (agx0 & 7)) & 0xfu;
            unsigned int db = ((ads & 0xffu) ? 0x3u : 0u) | ((ads & 0xff00u) ? 0xcu : 0u);
            unsigned int src = db & ~nib & 0xfu;     // corners never in halo
            ww = enc_w(src, nib);
            vv.x = (src & 1u) ? axx.x : 0.0f;
            vv.y = (src & 2u) ? axx.y : 0.0f;
            vv.z = (src & 4u) ? axx.z : 0.0f;
            vv.w = (src & 8u) ? axx.w : 0.0f;
            fNA = ~src & 0xfu; iNA = nib;
        }
        *reinterpret_cast<float4*>(&v[P0A]) = vv;
        w32[P0A >> 2] = ww;
    }
    P0B = (bly + 1) * PRW + 4 + blxg * 4;
    if (hasB) {   // halo B (tid < 64)
        float4 vv = make_float4(0.f, 0.f, 0.f, 0.f);
        unsigned int ww = 0x7f7f7f7fu;
        if (bin) {
            unsigned int nib = (bmb >> (bgx0 & 7)) & 0xfu;
            unsigned int db = ((bds & 0xffu) ? 0x3u : 0u) | ((bds & 0xff00u) ? 0xcu : 0u);
            unsigned int src = db & ~nib & 0xfu;
            ww = enc_w(src, nib);
            vv.x = (src & 1u) ? bxx.x : 0.0f;
            vv.y = (src & 2u) ? bxx.y : 0.0f;
            vv.z = (src & 4u) ? bxx.z : 0.0f;
            vv.w = (src & 8u) ? bxx.w : 0.0f;
            fNB = ~src & 0xfu; iNB = nib;
        }
        *reinterpret_cast<float4*>(&v[P0B]) = vv;
        w32[P0B >> 2] = ww;
    }

    // ---- wave-compacted worklist build (prefix-sum + 1 atomic per wave) ----
    int cnt = __popc(fN0) + __popc(fN1) + __popc(fNA) + __popc(fNB);
    int lane = tid & 63;
    int xsum = cnt;
#pragma unroll
    for (int d = 1; d < 64; d <<= 1) {
        int y = __shfl_up(xsum, d, 64);
        if (lane >= d) xsum += y;
    }
    int base = 0;
    if (lane == 63) base = atomicAdd(&qn, xsum);
    base = __shfl(base, 63, 64);
    int idx = base + (xsum - cnt);
#define PUSH(m_, iv_, pd_, gp_) { unsigned int m = (m_); while (m) {            \
        int b = __builtin_ctz(m); m &= m - 1;                                   \
        unsigned int e = (unsigned int)((gp_) + b) | ((((iv_) >> b) & 1u) << 14)\
                         | ((((pd_) >> b) & 1u) << 15);                         \
        if (idx < QCAP) q[idx] = (unsigned short)e; ++idx; } }
    PUSH(fN0, iN0, fN0 & iN0, P0i0)        // interior: pend = fillable & invalid
    PUSH(fN1, iN1, fN1 & iN1, P0i1)
    PUSH(fNA, iNA, 0u, P0A)                // halo: never pend-relevant
    PUSH(fNB, iNB, 0u, P0B)
#undef PUSH
    __syncthreads();

    const int n = qn;
    if (n <= QCAP) {
        // ---- worklist Jacobi: 1 px/lane, packed; skip filled via state byte ----
        for (int it = 0; it < 8; ++it) {
            int chg = 0, pend = 0;
            unsigned int thr = (unsigned int)it;
            for (int i = tid; i < n; i += 512) {
                unsigned int e = q[i];
                int p = e & 0x1fffu;
                if (w[p] & 0x7fu) continue;            // already filled
                unsigned int qu = w[p - PRW] & 0x7fu;
                unsigned int qd = w[p + PRW] & 0x7fu;
                unsigned int ql = w[p - 1]   & 0x7fu;
                unsigned int qr = w[p + 1]   & 0x7fu;
                bool su = (qu - 1u) <= thr, sd = (qd - 1u) <= thr;
                bool sl = (ql - 1u) <= thr, sr = (qr - 1u) <= thr;
                float s = (su ? v[p - PRW] : 0.0f) + (sd ? v[p + PRW] : 0.0f)
                        + (sl ? v[p - 1]   : 0.0f) + (sr ? v[p + 1]   : 0.0f);
                int cn = (int)su + (int)sd + (int)sl + (int)sr;
                if (cn > 0) {
                    v[p] = s / (float)cn;              // reads gated by old states
                    w[p] = (unsigned char)((((e >> 14) & 1u) << 7) | (unsigned int)(it + 2));
                    chg = 1;
                } else {
                    pend |= (int)((e >> 15) & 1u);
                }
            }
            if (chg)  chgf[it] = 1;                    // benign all-write-1 races
            if (pend) pendf[it] = 1;
            __syncthreads();
            if (chgf[it] == 0 || pendf[it] == 0) break;
        }
    } else {
        // ---- overflow fallback (~never): dense sweeps over all words ----
        for (int it = 0; it < 8; ++it) {
            int chg = 0;
            unsigned int thr = (unsigned int)it;
            for (int wp = tid; wp < PWORDS; wp += 512) {
                unsigned int cw = w32[wp];
                unsigned int st = cw & 0x7f7f7f7fu;
                if ((((st - 0x01010101u) & ~st) & 0x80808080u) == 0u) continue;
                int p0 = wp * 4;
#pragma unroll
                for (int b = 0; b < 4; ++b) {
                    if (((st >> (8 * b)) & 0x7fu) != 0u) continue;  // exact per-byte
                    int p = p0 + b;
                    unsigned int qu = w[p - PRW] & 0x7fu, qd = w[p + PRW] & 0x7fu;
                    unsigned int ql = w[p - 1] & 0x7fu,   qr = w[p + 1] & 0x7fu;
                    bool su = (qu - 1u) <= thr, sd = (qd - 1u) <= thr;
                    bool sl = (ql - 1u) <= thr, sr = (qr - 1u) <= thr;
                    float s = (su ? v[p - PRW] : 0.0f) + (sd ? v[p + PRW] : 0.0f)
                            + (sl ? v[p - 1]   : 0.0f) + (sr ? v[p + 1]   : 0.0f);
                    int cn = (int)su + (int)sd + (int)sl + (int)sr;
                    if (cn > 0) {
                        v[p] = s / (float)cn;
                        w[p] = (unsigned char)(((cw >> (8 * b)) & 0x80u) | (unsigned int)(it + 2));
                        chg = 1;
                    }
                }
            }
            if (chg) chgf[it] = 1;
            __syncthreads();
            if (chgf[it] == 0) break;
        }
    }

    // ---- epilogue: blended coalesced store, out = invalid ? v : x_reg ----
#pragma unroll
    for (int k = 0; k < 2; ++k) {
        int r  = r0 + k * 32;
        int p0 = (9 + r) * PRW + 12 + cg0 * 4;
        unsigned int cw = w32[p0 >> 2];
        float4 vv = *reinterpret_cast<const float4*>(&v[p0]);
        float4 xx = xr[k];
        float4 o;
        o.x = (cw & 0x00000080u) ? vv.x : xx.x;
        o.y = (cw & 0x00008000u) ? vv.y : xx.y;
        o.z = (cw & 0x00800000u) ? vv.z : xx.z;
        o.w = (cw & 0x80000000u) ? vv.w : xx.w;
        *reinterpret_cast<float4*>(oc + (by0 + r) * 1024 + bx0 + cg0 * 4) = o;
    }
}

extern "C" void kernel_launch(void* const* d_in, const int* in_sizes, int n_in,
                              void* d_out, int out_size, void* d_ws, size_t ws_size,
                              hipStream_t stream) {
    (void)in_sizes; (void)n_in; (void)out_size; (void)ws_size;
    const float* x      = (const float*)d_in[0];
    const float* hole_u = (const float*)d_in[1];
    float* out = (float*)d_out;
    unsigned char* u_small  = (unsigned char*)d_ws;           // 256 KiB
    unsigned char* d_small  = u_small + 262144;               // 256 KiB
    unsigned char* inv_mask = d_small + 262144;               // 2 MiB

    k_mask<<<8192, 256, 0, stream>>>(hole_u, inv_mask);       // 2M threads, 8 px each
    k_us  <<<256, 256, 0, stream>>>(inv_mask, u_small);
    k_dil <<<1024, 256, 0, stream>>>(u_small, d_small);
    dim3 grid(16, 16, 16);   // tiles_x, tiles_y, channels
    k_fill<<<grid, 512, 0, stream>>>(x, inv_mask, d_small, out);
}